// Round 17
// baseline (167.141 us; speedup 1.0000x reference)
//
#include <hip/hip_runtime.h>

typedef __attribute__((ext_vector_type(8))) short short8v;
typedef __attribute__((ext_vector_type(4))) float f32x4;
typedef __attribute__((ext_vector_type(16))) float f32x16;
typedef __attribute__((ext_vector_type(4))) int int4v;
typedef __attribute__((ext_vector_type(4))) unsigned int uint4v;
typedef __attribute__((ext_vector_type(4))) unsigned short u16x4;

#define MFMA16(a, b, c) __builtin_amdgcn_mfma_f32_16x16x32_bf16(a, b, c, 0, 0, 0)
#define MFMA32(a, b, c) __builtin_amdgcn_mfma_f32_32x32x16_bf16(a, b, c, 0, 0, 0)

__device__ __forceinline__ unsigned short f2bf(float f) {
  unsigned int u = __builtin_bit_cast(unsigned int, f);
  return (unsigned short)((u + 0x7FFFu + ((u >> 16) & 1u)) >> 16);
}
__device__ __forceinline__ float bf2f(unsigned short s) {
  return __builtin_bit_cast(float, (unsigned int)s << 16);
}
__device__ __forceinline__ float exp2_hw(float x) {
  float r;
  asm("v_exp_f32 %0, %1" : "=v"(r) : "v"(x));
  return r;
}
// async global->LDS, 16B/lane; lds base wave-uniform (HW adds lane*16)
__device__ __forceinline__ void gl_lds16(const unsigned short* g, unsigned short* l) {
  __builtin_amdgcn_global_load_lds(
      (const __attribute__((address_space(1))) void*)g,
      (__attribute__((address_space(3))) void*)l, 16, 0, 0);
}

// ---------------- all four fp32->bf16 casts in ONE launch ----------------
__global__ __launch_bounds__(256) void cast_all(
    const float* __restrict__ x, const float* __restrict__ wqkv,
    const float* __restrict__ wproj, const float* __restrict__ ab,
    unsigned short* __restrict__ xb, unsigned short* __restrict__ wqkvb,
    unsigned short* __restrict__ wprojb, unsigned short* __restrict__ biasb) {
  int i = blockIdx.x * 256 + threadIdx.x;  // 0 .. 3145727 (units of 4 floats)
  const float* src;
  unsigned short* dst;
  int off;
  float scale = 1.0f;
  if (i < 1048576) { src = x; dst = xb; off = i; }
  else if (i < 1835008) { src = wqkv; dst = wqkvb; off = i - 1048576; }
  else if (i < 2097152) { src = wproj; dst = wprojb; off = i - 1835008; }
  else { src = ab; dst = biasb; off = i - 2097152; scale = 1.44269504088896f; }
  f32x4 v = *(const f32x4*)(src + (size_t)off * 4);
  u16x4 o;
#pragma unroll
  for (int j = 0; j < 4; ++j) o[j] = f2bf(v[j] * scale);
  *(u16x4*)(dst + (size_t)off * 4) = o;
}

// ---------------- QKV GEMM: 8-phase 256x256 tile, counted-vmcnt pipeline ----------
// qkv = x @ w_qkv^T. BM=BN=256, BK=64, 8 waves (2x4), LDS 128KB double-buffered.
// Per K-tile: 4 phases = C-quadrants (0,0),(0,1),(1,1),(1,0); 16 MFMA each.
// Stage order for kt+1 (one half-tile per phase): A0@P0, B0@P1, B1@P2, A1@P3.
// Waits: vmcnt(4) at P0 (guarantees A0,B0,B1 of kt), vmcnt(6) at P2 (A1 of kt);
// never 0 in steady state (T4). Barriers: b1 pre-stage (slot-overwrite safety),
// b2/b3 post-wait (cross-wave visibility of gl_lds data).
// Epilogue: bias + l2-norm for q/k (direct stores, r16-proven); V via per-wave
// swizzled LDS transpose -> coalesced vt writes.
__global__ __launch_bounds__(512) void gemm_qkv(
    const unsigned short* __restrict__ A, const unsigned short* __restrict__ Bm,
    unsigned short* __restrict__ qn, unsigned short* __restrict__ kn,
    unsigned short* __restrict__ vt,
    const float* __restrict__ bias_q, const float* __restrict__ bias_v,
    const float* __restrict__ scale_mul) {
  __shared__ unsigned short Al[2][16384];  // [slot][256 rows x 64 k] (32KB/slot)
  __shared__ unsigned short Bl[2][16384];
  const int tid = threadIdx.x;   // 0..511
  const int lane = tid & 63;
  const int wave = tid >> 6;     // 0..7
  const int wr = wave >> 2;      // 0..1  (row half: 128 rows)
  const int wcn = wave & 3;      // 0..3  (col quarter: 64 cols)
  const int c = lane & 15, g = lane >> 4;
  const int rowBase = blockIdx.x * 256;
  const int colBase = blockIdx.y * 256;
  // staging geometry: round r (0..3) covers rows [r*64, r*64+64), this thread:
  const int srow = tid >> 3;            // 0..63 within round
  const int scol = (tid & 7) * 8;       // u16 col
  // LDS dest base for round r: u16 offset r*4096 + wave*512 (lane*8 implied)

  auto STAGE_A = [&](int kt, int half) {  // half-tile A<half> of tile kt
    int slot = kt & 1;
#pragma unroll
    for (int rr = 0; rr < 2; ++rr) {
      int r = half * 2 + rr;
      gl_lds16(A + (size_t)(rowBase + r * 64 + srow) * 1024 + kt * 64 + scol,
               &Al[slot][r * 4096 + wave * 512]);
    }
  };
  auto STAGE_B = [&](int kt, int half) {
    int slot = kt & 1;
#pragma unroll
    for (int rr = 0; rr < 2; ++rr) {
      int r = half * 2 + rr;
      gl_lds16(Bm + (size_t)(colBase + r * 64 + srow) * 1024 + kt * 64 + scol,
               &Bl[slot][r * 4096 + wave * 512]);
    }
  };

  f32x4 acc[8][4];
#pragma unroll
  for (int m = 0; m < 8; ++m)
#pragma unroll
    for (int n = 0; n < 4; ++n) acc[m][n] = (f32x4){0.f, 0.f, 0.f, 0.f};

  short8v af[4][2];  // A-frags of current m-half: [mm][kk]
  short8v bf[2][2];  // B-frags of current n-half: [nn][kk]

  // prologue: stage whole tile 0 in ledger order A0,B0,B1,A1
  STAGE_A(0, 0);
  STAGE_B(0, 0);
  STAGE_B(0, 1);
  STAGE_A(0, 1);

  for (int kt = 0; kt < 16; ++kt) {
    const int slot = kt & 1;
    const bool more = (kt + 1) < 16;

    // ---- P0: quadrant (0,0) ----
    __builtin_amdgcn_s_barrier();  // b1: all waves done reading slot^1 (kt-1)
    if (more) STAGE_A(kt + 1, 0);
    if (more) asm volatile("s_waitcnt vmcnt(4)" ::: "memory");
    else      asm volatile("s_waitcnt vmcnt(2)" ::: "memory");
    __builtin_amdgcn_s_barrier();  // b2: A0,B0,B1(kt) visible block-wide
#pragma unroll
    for (int mm = 0; mm < 4; ++mm)
#pragma unroll
      for (int kk = 0; kk < 2; ++kk)
        af[mm][kk] = *(const short8v*)
            &Al[slot][(wr * 128 + mm * 16 + c) * 64 + kk * 32 + g * 8];
#pragma unroll
    for (int nn = 0; nn < 2; ++nn)
#pragma unroll
      for (int kk = 0; kk < 2; ++kk)
        bf[nn][kk] = *(const short8v*)
            &Bl[slot][(wcn * 64 + nn * 16 + c) * 64 + kk * 32 + g * 8];
    __builtin_amdgcn_s_setprio(1);
#pragma unroll
    for (int mm = 0; mm < 4; ++mm)
#pragma unroll
      for (int nn = 0; nn < 2; ++nn)
#pragma unroll
        for (int kk = 0; kk < 2; ++kk)
          acc[mm][nn] = MFMA16(af[mm][kk], bf[nn][kk], acc[mm][nn]);
    __builtin_amdgcn_s_setprio(0);

    // ---- P1: quadrant (0,1) ----
    if (more) STAGE_B(kt + 1, 0);
#pragma unroll
    for (int nn = 0; nn < 2; ++nn)
#pragma unroll
      for (int kk = 0; kk < 2; ++kk)
        bf[nn][kk] = *(const short8v*)
            &Bl[slot][(wcn * 64 + (2 + nn) * 16 + c) * 64 + kk * 32 + g * 8];
    __builtin_amdgcn_s_setprio(1);
#pragma unroll
    for (int mm = 0; mm < 4; ++mm)
#pragma unroll
      for (int nn = 0; nn < 2; ++nn)
#pragma unroll
        for (int kk = 0; kk < 2; ++kk)
          acc[mm][2 + nn] = MFMA16(af[mm][kk], bf[nn][kk], acc[mm][2 + nn]);
    __builtin_amdgcn_s_setprio(0);

    // ---- P2: quadrant (1,1) ----
    if (more) STAGE_B(kt + 1, 1);
    if (more) asm volatile("s_waitcnt vmcnt(6)" ::: "memory");
    else      asm volatile("s_waitcnt vmcnt(0)" ::: "memory");
    __builtin_amdgcn_s_barrier();  // b3: A1(kt) visible block-wide
#pragma unroll
    for (int mm = 0; mm < 4; ++mm)
#pragma unroll
      for (int kk = 0; kk < 2; ++kk)
        af[mm][kk] = *(const short8v*)
            &Al[slot][(wr * 128 + (4 + mm) * 16 + c) * 64 + kk * 32 + g * 8];
    __builtin_amdgcn_s_setprio(1);
#pragma unroll
    for (int mm = 0; mm < 4; ++mm)
#pragma unroll
      for (int nn = 0; nn < 2; ++nn)
#pragma unroll
        for (int kk = 0; kk < 2; ++kk)
          acc[4 + mm][2 + nn] = MFMA16(af[mm][kk], bf[nn][kk], acc[4 + mm][2 + nn]);
    __builtin_amdgcn_s_setprio(0);

    // ---- P3: quadrant (1,0) ----
    if (more) STAGE_A(kt + 1, 1);
#pragma unroll
    for (int nn = 0; nn < 2; ++nn)
#pragma unroll
      for (int kk = 0; kk < 2; ++kk)
        bf[nn][kk] = *(const short8v*)
            &Bl[slot][(wcn * 64 + nn * 16 + c) * 64 + kk * 32 + g * 8];
    __builtin_amdgcn_s_setprio(1);
#pragma unroll
    for (int mm = 0; mm < 4; ++mm)
#pragma unroll
      for (int nn = 0; nn < 2; ++nn)
#pragma unroll
        for (int kk = 0; kk < 2; ++kk)
          acc[4 + mm][nn] = MFMA16(af[mm][kk], bf[nn][kk], acc[4 + mm][nn]);
    __builtin_amdgcn_s_setprio(0);
  }

  // ---------------- epilogue ----------------
  const int sec = colBase >> 10;                   // 0=q 1=k 2=v (block-uniform)
  const int jbase = (colBase & 1023) + wcn * 64;   // head-col base (wave-uniform)
  const int headCol = jbase >> 6;
  const int bI = rowBase >> 11;
  const int bhh = bI * 16 + headCol;

  if (sec == 2) {
    // V: bias add, per-wave swizzled LDS transpose (two 64x64 sub-tiles),
    // coalesced vt [B,H,D,L] writes. Scratch aliases Al (all compute done).
    __syncthreads();
    unsigned short* tls = &Al[0][0] + wave * 4096;  // per-wave 64x64 u16
#pragma unroll
    for (int lh = 0; lh < 2; ++lh) {
      const int lbase = (rowBase & 2047) + wr * 128 + lh * 64;
#pragma unroll
      for (int mq = 0; mq < 4; ++mq)
#pragma unroll
        for (int r = 0; r < 4; ++r)
#pragma unroll
          for (int n = 0; n < 4; ++n) {
            int d = n * 16 + c;
            int ll = mq * 16 + g * 4 + r;
            tls[d * 64 + (ll ^ ((d & 7) << 3))] =
                f2bf(acc[lh * 4 + mq][n][r] + bias_v[jbase + n * 16 + c]);
          }
      // per-wave-private region: compiler lgkm ordering suffices (no barrier)
#pragma unroll
      for (int j = 0; j < 8; ++j) {
        int idx = j * 64 + lane;
        int d = idx >> 3;
        int l8 = (idx & 7) * 8;
        short8v v8 = *(const short8v*)&tls[d * 64 + (l8 ^ ((d & 7) << 3))];
        *(short8v*)(vt + ((size_t)(bhh * 64 + d)) * 2048 + lbase + l8) = v8;
      }
    }
  } else {
    float qsc = 1.0f;
    if (sec == 0)
      qsc = __expf(fminf(scale_mul[headCol], 4.605170185988091f)) * 1.44269504088896f;
#pragma unroll
    for (int m = 0; m < 8; ++m) {
#pragma unroll
      for (int r = 0; r < 4; ++r) {
        float vv[4];
#pragma unroll
        for (int n = 0; n < 4; ++n) {
          int jn = jbase + n * 16 + c;
          float bias = (sec == 0) ? bias_q[jn] : 0.0f;
          vv[n] = acc[m][n][r] + bias;
        }
        // l2-norm across the 64 d-values of this row-head (4 regs x 16 c-lanes)
        float ss = vv[0] * vv[0] + vv[1] * vv[1] + vv[2] * vv[2] + vv[3] * vv[3];
        ss += __shfl_xor(ss, 1);
        ss += __shfl_xor(ss, 2);
        ss += __shfl_xor(ss, 4);
        ss += __shfl_xor(ss, 8);
        float sc = qsc / fmaxf(sqrtf(ss), 1e-12f);
        int grow = rowBase + wr * 128 + m * 16 + g * 4 + r;
        int l = grow & 2047;
#pragma unroll
        for (int n = 0; n < 4; ++n) {
          int d = n * 16 + c;
          unsigned short o = f2bf(vv[n] * sc);
          if (sec == 0)
            qn[(bhh * 2048 + l) * 64 + d] = o;
          else
            kn[(bhh * 2048 + l) * 64 + d] = o;
        }
      }
    }
  }
}

// ---------------- proj GEMM: out = oup @ w_proj^T + b_proj (fp32 out) ----------
// 64x64 tile -> grid (64,16) = 1024 blocks = 4 blocks/CU (LDS 16KB, acc[2][2]).
__global__ __launch_bounds__(256) void gemm_proj(
    const unsigned short* __restrict__ A, const unsigned short* __restrict__ Bm,
    float* __restrict__ outf, const float* __restrict__ bias) {
  __shared__ unsigned short Asl[64 * 64];   // 8KB
  __shared__ unsigned short Bsl[64 * 64];   // 8KB
  const int tid = threadIdx.x;
  const int lane = tid & 63;
  const int wave = tid >> 6;
  const int wr = wave >> 1, wc = wave & 1;
  const int c = lane & 15, g = lane >> 4;
  const int rowBase = blockIdx.x * 64;
  const int colBase = blockIdx.y * 64;
  const int srow = lane >> 3, scol = (lane & 7) * 8;

  f32x4 acc[2][2];
#pragma unroll
  for (int m = 0; m < 2; ++m)
#pragma unroll
    for (int n = 0; n < 2; ++n) acc[m][n] = (f32x4){0.f, 0.f, 0.f, 0.f};

  for (int k0 = 0; k0 < 1024; k0 += 64) {
#pragma unroll
    for (int it = 0; it < 2; ++it) {
      int ci = wave * 2 + it;
      int r = ci * 8 + srow;
      gl_lds16(A + (size_t)(rowBase + r) * 1024 + k0 + scol, &Asl[ci * 512]);
      gl_lds16(Bm + (size_t)(colBase + r) * 1024 + k0 + scol, &Bsl[ci * 512]);
    }
    __syncthreads();
#pragma unroll
    for (int kk = 0; kk < 2; ++kk) {
      short8v af[2], bfr[2];
#pragma unroll
      for (int m = 0; m < 2; ++m)
        af[m] = *(const short8v*)&Asl[(wr * 32 + m * 16 + c) * 64 + kk * 32 + g * 8];
#pragma unroll
      for (int n = 0; n < 2; ++n)
        bfr[n] = *(const short8v*)&Bsl[(wc * 32 + n * 16 + c) * 64 + kk * 32 + g * 8];
#pragma unroll
      for (int m = 0; m < 2; ++m)
#pragma unroll
        for (int n = 0; n < 2; ++n) acc[m][n] = MFMA16(af[m], bfr[n], acc[m][n]);
    }
    __syncthreads();
  }

#pragma unroll
  for (int m = 0; m < 2; ++m)
#pragma unroll
    for (int n = 0; n < 2; ++n)
#pragma unroll
      for (int r = 0; r < 4; ++r) {
        int grow = rowBase + wr * 32 + m * 16 + g * 4 + r;
        int gcol = colBase + wc * 32 + n * 16 + c;
        outf[(size_t)grow * 1024 + gcol] = acc[m][n][r] + bias[gcol];
      }
}

// ---------------- flash attention: KV tile 128 (r13, 85.4us plateau) ----------------
// No-max softmax (scores bounded: |S*log2e| <= 5.9 by l2-norm construction).
// 4 waves x 32 q-rows = 128 q/block; KV tile 128 (4 sequential 32-k subtiles).
// NOTE: no min-waves launch bound ((256,4) caused 300MB scratch spills, r6-7).
__global__ __launch_bounds__(256) void attn_fwd(
    const unsigned short* __restrict__ qn, const unsigned short* __restrict__ kn,
    const unsigned short* __restrict__ vt, const unsigned short* __restrict__ biasb,
    unsigned short* __restrict__ oup) {
  __shared__ unsigned short Ksl[2][128][72];
  __shared__ unsigned short Vsl[2][64][136];
  const int tid = threadIdx.x;
  const int lane = tid & 63;
  const int wave = tid >> 6;
  const int c5 = lane & 31;
  const int h = lane >> 5;
  const int qt = blockIdx.x;   // 16
  const int bh = blockIdx.y;   // 32
  const int b = bh >> 4, hd = bh & 15;
  const int q = qt * 128 + wave * 32 + c5;

  short8v qf[4];
  {
    const unsigned short* qp = qn + ((size_t)bh * 2048 + q) * 64 + h * 8;
#pragma unroll
    for (int kd = 0; kd < 4; ++kd) qf[kd] = *(const short8v*)(qp + kd * 16);
  }
  const unsigned short* kb = kn + (size_t)bh * 131072;
  const unsigned short* vb = vt + (size_t)bh * 131072;
  const unsigned short* bq = biasb + (size_t)q * 2048 + h * 4;

  int rk[4], ck[4], rv[4], cv[4];
#pragma unroll
  for (int i = 0; i < 4; ++i) {
    int flat = tid * 8 + i * 2048;
    rk[i] = flat >> 6;  ck[i] = flat & 63;
    rv[i] = flat >> 7;  cv[i] = flat & 127;
  }

  int4v kreg[4], vreg[4];
  u16x4 bb[4][4];

  auto ISSUE = [&](int kt) {
#pragma unroll
    for (int i = 0; i < 4; ++i) {
      kreg[i] = *(const int4v*)(kb + (size_t)(kt * 128 + rk[i]) * 64 + ck[i]);
      vreg[i] = *(const int4v*)(vb + (size_t)rv[i] * 2048 + kt * 128 + cv[i]);
    }
  };
  auto ISSUEB = [&](int n, int kt) {
#pragma unroll
    for (int Qd = 0; Qd < 4; ++Qd)
      bb[n][Qd] = *(const u16x4*)(bq + kt * 128 + n * 32 + Qd * 8);
  };
  auto WRITE = [&](int buf) {
#pragma unroll
    for (int i = 0; i < 4; ++i) {
      *(int4v*)&Ksl[buf][rk[i]][ck[i]] = kreg[i];
      *(int4v*)&Vsl[buf][rv[i]][cv[i]] = vreg[i];
    }
  };

  float l_run = 0.0f;
  f32x16 o0 = {}, o1 = {};

  ISSUE(0);
#pragma unroll
  for (int n = 0; n < 4; ++n) ISSUEB(n, 0);
  WRITE(0);
  __syncthreads();

  for (int kt = 0; kt < 16; ++kt) {
    const int cur = kt & 1;
    const bool more = (kt + 1) < 16;
    if (more) ISSUE(kt + 1);
    float rs = 0.0f;

#pragma unroll
    for (int n = 0; n < 4; ++n) {
      f32x16 s;
#pragma unroll
      for (int Qd = 0; Qd < 4; ++Qd)
#pragma unroll
        for (int r = 0; r < 4; ++r) s[Qd * 4 + r] = bf2f(bb[n][Qd][r]);
      if (more) ISSUEB(n, kt + 1);

      __builtin_amdgcn_s_setprio(1);
#pragma unroll
      for (int kd = 0; kd < 4; ++kd) {
        short8v kf = *(const short8v*)&Ksl[cur][n * 32 + c5][kd * 16 + h * 8];
        s = MFMA32(kf, qf[kd], s);
      }
      __builtin_amdgcn_s_setprio(0);

#pragma unroll
      for (int e = 0; e < 16; ++e) {
        float p = exp2_hw(s[e]);
        s[e] = p;
        rs += p;
      }

      unsigned int w[4][2];
#pragma unroll
      for (int Qd = 0; Qd < 4; ++Qd) {
        asm("v_cvt_pk_bf16_f32 %0, %1, %2"
            : "=v"(w[Qd][0]) : "v"(s[Qd * 4 + 0]), "v"(s[Qd * 4 + 1]));
        asm("v_cvt_pk_bf16_f32 %0, %1, %2"
            : "=v"(w[Qd][1]) : "v"(s[Qd * 4 + 2]), "v"(s[Qd * 4 + 3]));
      }

      __builtin_amdgcn_s_setprio(1);
#pragma unroll
      for (int kc = 0; kc < 2; ++kc) {
        unsigned int W[4];
#pragma unroll
        for (int u = 0; u < 2; ++u) {
          unsigned int A = w[kc * 2][u];
          unsigned int B = w[kc * 2 + 1][u];
          unsigned int pub = h ? A : B;
          unsigned int ex = (unsigned int)__shfl_xor((int)pub, 32);
          W[u] = h ? ex : A;
          W[2 + u] = h ? B : ex;
        }
        uint4v wv = {W[0], W[1], W[2], W[3]};
        short8v pa = __builtin_bit_cast(short8v, wv);
        short8v v0 = *(const short8v*)&Vsl[cur][c5][n * 32 + kc * 16 + h * 8];
        short8v v1 = *(const short8v*)&Vsl[cur][32 + c5][n * 32 + kc * 16 + h * 8];
        o0 = MFMA32(pa, v0, o0);
        o1 = MFMA32(pa, v1, o1);
      }
      __builtin_amdgcn_s_setprio(0);
    }

    rs += __shfl_xor(rs, 32);
    l_run += rs;

    if (more) WRITE(cur ^ 1);
    __syncthreads();
  }

  float linv = 1.0f / l_run;
#pragma unroll
  for (int e = 0; e < 16; ++e) {
    int ql = (e & 3) + 8 * (e >> 2) + 4 * h;
    float inv = __shfl(linv, ql);
    int grow = b * 2048 + qt * 128 + wave * 32 + ql;
    oup[(size_t)grow * 1024 + hd * 64 + c5] = f2bf(o0[e] * inv);
    oup[(size_t)grow * 1024 + hd * 64 + 32 + c5] = f2bf(o1[e] * inv);
  }
}

// ---------------- host launch ----------------
extern "C" void kernel_launch(void* const* d_in, const int* in_sizes, int n_in,
                              void* d_out, int out_size, void* d_ws, size_t ws_size,
                              hipStream_t stream) {
  const float* x = (const float*)d_in[0];
  const float* attn_bias = (const float*)d_in[1];
  const float* w_qkv = (const float*)d_in[2];
  const float* q_bias = (const float*)d_in[3];
  const float* v_bias = (const float*)d_in[4];
  const float* scale_mul = (const float*)d_in[5];
  const float* w_proj = (const float*)d_in[6];
  const float* b_proj = (const float*)d_in[7];
  float* out = (float*)d_out;

  char* ws = (char*)d_ws;
  unsigned short* xb = (unsigned short*)(ws);                   // [4096][1024] bf16
  unsigned short* oup = (unsigned short*)(ws);                  // alias (disjoint lifetime)
  unsigned short* wqkvb = (unsigned short*)(ws + (8 << 20));    // [3072][1024]
  unsigned short* wprojb = (unsigned short*)(ws + (14 << 20));  // [1024][1024]
  unsigned short* biasb = (unsigned short*)(ws + (16 << 20));   // [2048][2048] (*log2e)
  unsigned short* qn = (unsigned short*)(ws + (24 << 20));      // [32][2048][64]
  unsigned short* kn = (unsigned short*)(ws + (32 << 20));      // [32][2048][64]
  unsigned short* vt = (unsigned short*)(ws + (40 << 20));      // [32][64][2048]

  cast_all<<<12288, 256, 0, stream>>>(x, w_qkv, w_proj, attn_bias, xb, wqkvb,
                                      wprojb, biasb);
  gemm_qkv<<<dim3(16, 12), 512, 0, stream>>>(xb, wqkvb, qn, kn, vt, q_bias,
                                             v_bias, scale_mul);
  attn_fwd<<<dim3(16, 32), 256, 0, stream>>>(qn, kn, vt, biasb, oup);
  gemm_proj<<<dim3(64, 16), 256, 0, stream>>>(oup, wprojb, out, b_proj);
}

// Round 18
// 160.610 us; speedup vs baseline: 1.0407x; 1.0407x over previous
//
#include <hip/hip_runtime.h>

typedef __attribute__((ext_vector_type(8))) short short8v;
typedef __attribute__((ext_vector_type(4))) float f32x4;
typedef __attribute__((ext_vector_type(16))) float f32x16;
typedef __attribute__((ext_vector_type(4))) int int4v;
typedef __attribute__((ext_vector_type(4))) unsigned int uint4v;
typedef __attribute__((ext_vector_type(4))) unsigned short u16x4;

#define MFMA16(a, b, c) __builtin_amdgcn_mfma_f32_16x16x32_bf16(a, b, c, 0, 0, 0)
#define MFMA32(a, b, c) __builtin_amdgcn_mfma_f32_32x32x16_bf16(a, b, c, 0, 0, 0)

__device__ __forceinline__ unsigned short f2bf(float f) {
  unsigned int u = __builtin_bit_cast(unsigned int, f);
  return (unsigned short)((u + 0x7FFFu + ((u >> 16) & 1u)) >> 16);
}
__device__ __forceinline__ float bf2f(unsigned short s) {
  return __builtin_bit_cast(float, (unsigned int)s << 16);
}
__device__ __forceinline__ float exp2_hw(float x) {
  float r;
  asm("v_exp_f32 %0, %1" : "=v"(r) : "v"(x));
  return r;
}
// async global->LDS, 16B/lane; lds base wave-uniform (HW adds lane*16)
__device__ __forceinline__ void gl_lds16(const unsigned short* g, unsigned short* l) {
  __builtin_amdgcn_global_load_lds(
      (const __attribute__((address_space(1))) void*)g,
      (__attribute__((address_space(3))) void*)l, 16, 0, 0);
}

// ---------------- all four fp32->bf16 casts in ONE launch ----------------
__global__ __launch_bounds__(256) void cast_all(
    const float* __restrict__ x, const float* __restrict__ wqkv,
    const float* __restrict__ wproj, const float* __restrict__ ab,
    unsigned short* __restrict__ xb, unsigned short* __restrict__ wqkvb,
    unsigned short* __restrict__ wprojb, unsigned short* __restrict__ biasb) {
  int i = blockIdx.x * 256 + threadIdx.x;  // 0 .. 3145727 (units of 4 floats)
  const float* src;
  unsigned short* dst;
  int off;
  float scale = 1.0f;
  if (i < 1048576) { src = x; dst = xb; off = i; }
  else if (i < 1835008) { src = wqkv; dst = wqkvb; off = i - 1048576; }
  else if (i < 2097152) { src = wproj; dst = wprojb; off = i - 1835008; }
  else { src = ab; dst = biasb; off = i - 2097152; scale = 1.44269504088896f; }
  f32x4 v = *(const f32x4*)(src + (size_t)off * 4);
  u16x4 o;
#pragma unroll
  for (int j = 0; j < 4; ++j) o[j] = f2bf(v[j] * scale);
  *(u16x4*)(dst + (size_t)off * 4) = o;
}

// ---------------- QKV GEMM: 8-phase 256x256 + T2 LDS XOR-swizzle ----------------
// qkv = x @ w_qkv^T. Same counted-vmcnt pipeline as r17. NEW: T21 both-sides
// swizzle (LDS dest linear; global SOURCE col pre-swizzled by ((tid&7)^(srow&7));
// reads XOR col_u16 with (row&7)<<3). Kills the 16-way ds_read bank conflict
// (lanes 0-15 at 128B row stride all hit bank 0 in linear layout) -> 2-way (free).
__global__ __launch_bounds__(512) void gemm_qkv(
    const unsigned short* __restrict__ A, const unsigned short* __restrict__ Bm,
    unsigned short* __restrict__ qn, unsigned short* __restrict__ kn,
    unsigned short* __restrict__ vt,
    const float* __restrict__ bias_q, const float* __restrict__ bias_v,
    const float* __restrict__ scale_mul) {
  __shared__ unsigned short Al[2][16384];  // [slot][256 rows x 64 k] (32KB/slot)
  __shared__ unsigned short Bl[2][16384];
  const int tid = threadIdx.x;   // 0..511
  const int lane = tid & 63;
  const int wave = tid >> 6;     // 0..7
  const int wr = wave >> 2;      // 0..1  (row half: 128 rows)
  const int wcn = wave & 3;      // 0..3  (col quarter: 64 cols)
  const int c = lane & 15, g = lane >> 4;
  const int rowBase = blockIdx.x * 256;
  const int colBase = blockIdx.y * 256;
  // staging geometry: round r covers rows [r*64, r*64+64); this thread:
  const int srow = tid >> 3;                          // 0..63 within round
  const int scol = (((tid & 7) ^ (srow & 7)) * 8);    // u16 col, PRE-SWIZZLED (T21)

  auto STAGE_A = [&](int kt, int half) {
    int slot = kt & 1;
#pragma unroll
    for (int rr = 0; rr < 2; ++rr) {
      int r = half * 2 + rr;
      gl_lds16(A + (size_t)(rowBase + r * 64 + srow) * 1024 + kt * 64 + scol,
               &Al[slot][r * 4096 + wave * 512]);
    }
  };
  auto STAGE_B = [&](int kt, int half) {
    int slot = kt & 1;
#pragma unroll
    for (int rr = 0; rr < 2; ++rr) {
      int r = half * 2 + rr;
      gl_lds16(Bm + (size_t)(colBase + r * 64 + srow) * 1024 + kt * 64 + scol,
               &Bl[slot][r * 4096 + wave * 512]);
    }
  };
  // swizzled fragment read: row-major [row][64 u16], col XOR (row&7)<<3
  auto LDA = [&](int slot, int row, int colu) -> short8v {
    return *(const short8v*)&Al[slot][row * 64 + (colu ^ ((row & 7) << 3))];
  };
  auto LDB = [&](int slot, int row, int colu) -> short8v {
    return *(const short8v*)&Bl[slot][row * 64 + (colu ^ ((row & 7) << 3))];
  };

  f32x4 acc[8][4];
#pragma unroll
  for (int m = 0; m < 8; ++m)
#pragma unroll
    for (int n = 0; n < 4; ++n) acc[m][n] = (f32x4){0.f, 0.f, 0.f, 0.f};

  short8v af[4][2];
  short8v bf[2][2];

  // prologue: stage whole tile 0 in ledger order A0,B0,B1,A1
  STAGE_A(0, 0);
  STAGE_B(0, 0);
  STAGE_B(0, 1);
  STAGE_A(0, 1);

  for (int kt = 0; kt < 16; ++kt) {
    const int slot = kt & 1;
    const bool more = (kt + 1) < 16;

    // ---- P0: quadrant (0,0) ----
    __builtin_amdgcn_s_barrier();  // b1: all waves done reading slot^1 (kt-1)
    if (more) STAGE_A(kt + 1, 0);
    if (more) asm volatile("s_waitcnt vmcnt(4)" ::: "memory");
    else      asm volatile("s_waitcnt vmcnt(2)" ::: "memory");
    __builtin_amdgcn_s_barrier();  // b2: A0,B0,B1(kt) visible block-wide
#pragma unroll
    for (int mm = 0; mm < 4; ++mm)
#pragma unroll
      for (int kk = 0; kk < 2; ++kk)
        af[mm][kk] = LDA(slot, wr * 128 + mm * 16 + c, kk * 32 + g * 8);
#pragma unroll
    for (int nn = 0; nn < 2; ++nn)
#pragma unroll
      for (int kk = 0; kk < 2; ++kk)
        bf[nn][kk] = LDB(slot, wcn * 64 + nn * 16 + c, kk * 32 + g * 8);
    __builtin_amdgcn_s_setprio(1);
#pragma unroll
    for (int mm = 0; mm < 4; ++mm)
#pragma unroll
      for (int nn = 0; nn < 2; ++nn)
#pragma unroll
        for (int kk = 0; kk < 2; ++kk)
          acc[mm][nn] = MFMA16(af[mm][kk], bf[nn][kk], acc[mm][nn]);
    __builtin_amdgcn_s_setprio(0);

    // ---- P1: quadrant (0,1) ----
    if (more) STAGE_B(kt + 1, 0);
#pragma unroll
    for (int nn = 0; nn < 2; ++nn)
#pragma unroll
      for (int kk = 0; kk < 2; ++kk)
        bf[nn][kk] = LDB(slot, wcn * 64 + (2 + nn) * 16 + c, kk * 32 + g * 8);
    __builtin_amdgcn_s_setprio(1);
#pragma unroll
    for (int mm = 0; mm < 4; ++mm)
#pragma unroll
      for (int nn = 0; nn < 2; ++nn)
#pragma unroll
        for (int kk = 0; kk < 2; ++kk)
          acc[mm][2 + nn] = MFMA16(af[mm][kk], bf[nn][kk], acc[mm][2 + nn]);
    __builtin_amdgcn_s_setprio(0);

    // ---- P2: quadrant (1,1) ----
    if (more) STAGE_B(kt + 1, 1);
    if (more) asm volatile("s_waitcnt vmcnt(6)" ::: "memory");
    else      asm volatile("s_waitcnt vmcnt(0)" ::: "memory");
    __builtin_amdgcn_s_barrier();  // b3: A1(kt) visible block-wide
#pragma unroll
    for (int mm = 0; mm < 4; ++mm)
#pragma unroll
      for (int kk = 0; kk < 2; ++kk)
        af[mm][kk] = LDA(slot, wr * 128 + (4 + mm) * 16 + c, kk * 32 + g * 8);
    __builtin_amdgcn_s_setprio(1);
#pragma unroll
    for (int mm = 0; mm < 4; ++mm)
#pragma unroll
      for (int nn = 0; nn < 2; ++nn)
#pragma unroll
        for (int kk = 0; kk < 2; ++kk)
          acc[4 + mm][2 + nn] = MFMA16(af[mm][kk], bf[nn][kk], acc[4 + mm][2 + nn]);
    __builtin_amdgcn_s_setprio(0);

    // ---- P3: quadrant (1,0) ----
    if (more) STAGE_A(kt + 1, 1);
#pragma unroll
    for (int nn = 0; nn < 2; ++nn)
#pragma unroll
      for (int kk = 0; kk < 2; ++kk)
        bf[nn][kk] = LDB(slot, wcn * 64 + nn * 16 + c, kk * 32 + g * 8);
    __builtin_amdgcn_s_setprio(1);
#pragma unroll
    for (int mm = 0; mm < 4; ++mm)
#pragma unroll
      for (int nn = 0; nn < 2; ++nn)
#pragma unroll
        for (int kk = 0; kk < 2; ++kk)
          acc[4 + mm][nn] = MFMA16(af[mm][kk], bf[nn][kk], acc[4 + mm][nn]);
    __builtin_amdgcn_s_setprio(0);
  }

  // ---------------- epilogue ----------------
  const int sec = colBase >> 10;                   // 0=q 1=k 2=v (block-uniform)
  const int jbase = (colBase & 1023) + wcn * 64;   // head-col base (wave-uniform)
  const int headCol = jbase >> 6;
  const int bI = rowBase >> 11;
  const int bhh = bI * 16 + headCol;

  if (sec == 2) {
    // V: bias add, per-wave swizzled LDS transpose (two 64x64 sub-tiles),
    // coalesced vt [B,H,D,L] writes. Scratch aliases Al (all compute done).
    __syncthreads();
    unsigned short* tls = &Al[0][0] + wave * 4096;  // per-wave 64x64 u16
#pragma unroll
    for (int lh = 0; lh < 2; ++lh) {
      const int lbase = (rowBase & 2047) + wr * 128 + lh * 64;
#pragma unroll
      for (int mq = 0; mq < 4; ++mq)
#pragma unroll
        for (int r = 0; r < 4; ++r)
#pragma unroll
          for (int n = 0; n < 4; ++n) {
            int d = n * 16 + c;
            int ll = mq * 16 + g * 4 + r;
            tls[d * 64 + (ll ^ ((d & 7) << 3))] =
                f2bf(acc[lh * 4 + mq][n][r] + bias_v[jbase + n * 16 + c]);
          }
      // per-wave-private region: compiler lgkm ordering suffices (no barrier)
#pragma unroll
      for (int j = 0; j < 8; ++j) {
        int idx = j * 64 + lane;
        int d = idx >> 3;
        int l8 = (idx & 7) * 8;
        short8v v8 = *(const short8v*)&tls[d * 64 + (l8 ^ ((d & 7) << 3))];
        *(short8v*)(vt + ((size_t)(bhh * 64 + d)) * 2048 + lbase + l8) = v8;
      }
    }
  } else {
    float qsc = 1.0f;
    if (sec == 0)
      qsc = __expf(fminf(scale_mul[headCol], 4.605170185988091f)) * 1.44269504088896f;
#pragma unroll
    for (int m = 0; m < 8; ++m) {
#pragma unroll
      for (int r = 0; r < 4; ++r) {
        float vv[4];
#pragma unroll
        for (int n = 0; n < 4; ++n) {
          int jn = jbase + n * 16 + c;
          float bias = (sec == 0) ? bias_q[jn] : 0.0f;
          vv[n] = acc[m][n][r] + bias;
        }
        // l2-norm across the 64 d-values of this row-head (4 regs x 16 c-lanes)
        float ss = vv[0] * vv[0] + vv[1] * vv[1] + vv[2] * vv[2] + vv[3] * vv[3];
        ss += __shfl_xor(ss, 1);
        ss += __shfl_xor(ss, 2);
        ss += __shfl_xor(ss, 4);
        ss += __shfl_xor(ss, 8);
        float sc = qsc / fmaxf(sqrtf(ss), 1e-12f);
        int grow = rowBase + wr * 128 + m * 16 + g * 4 + r;
        int l = grow & 2047;
#pragma unroll
        for (int n = 0; n < 4; ++n) {
          int d = n * 16 + c;
          unsigned short o = f2bf(vv[n] * sc);
          if (sec == 0)
            qn[(bhh * 2048 + l) * 64 + d] = o;
          else
            kn[(bhh * 2048 + l) * 64 + d] = o;
        }
      }
    }
  }
}

// ---------------- proj GEMM: out = oup @ w_proj^T + b_proj (fp32 out) ----------
// 64x64 tile -> grid (64,16) = 1024 blocks = 4 blocks/CU (LDS 16KB, acc[2][2]).
__global__ __launch_bounds__(256) void gemm_proj(
    const unsigned short* __restrict__ A, const unsigned short* __restrict__ Bm,
    float* __restrict__ outf, const float* __restrict__ bias) {
  __shared__ unsigned short Asl[64 * 64];   // 8KB
  __shared__ unsigned short Bsl[64 * 64];   // 8KB
  const int tid = threadIdx.x;
  const int lane = tid & 63;
  const int wave = tid >> 6;
  const int wr = wave >> 1, wc = wave & 1;
  const int c = lane & 15, g = lane >> 4;
  const int rowBase = blockIdx.x * 64;
  const int colBase = blockIdx.y * 64;
  const int srow = lane >> 3, scol = (lane & 7) * 8;

  f32x4 acc[2][2];
#pragma unroll
  for (int m = 0; m < 2; ++m)
#pragma unroll
    for (int n = 0; n < 2; ++n) acc[m][n] = (f32x4){0.f, 0.f, 0.f, 0.f};

  for (int k0 = 0; k0 < 1024; k0 += 64) {
#pragma unroll
    for (int it = 0; it < 2; ++it) {
      int ci = wave * 2 + it;
      int r = ci * 8 + srow;
      gl_lds16(A + (size_t)(rowBase + r) * 1024 + k0 + scol, &Asl[ci * 512]);
      gl_lds16(Bm + (size_t)(colBase + r) * 1024 + k0 + scol, &Bsl[ci * 512]);
    }
    __syncthreads();
#pragma unroll
    for (int kk = 0; kk < 2; ++kk) {
      short8v af[2], bfr[2];
#pragma unroll
      for (int m = 0; m < 2; ++m)
        af[m] = *(const short8v*)&Asl[(wr * 32 + m * 16 + c) * 64 + kk * 32 + g * 8];
#pragma unroll
      for (int n = 0; n < 2; ++n)
        bfr[n] = *(const short8v*)&Bsl[(wc * 32 + n * 16 + c) * 64 + kk * 32 + g * 8];
#pragma unroll
      for (int m = 0; m < 2; ++m)
#pragma unroll
        for (int n = 0; n < 2; ++n) acc[m][n] = MFMA16(af[m], bfr[n], acc[m][n]);
    }
    __syncthreads();
  }

#pragma unroll
  for (int m = 0; m < 2; ++m)
#pragma unroll
    for (int n = 0; n < 2; ++n)
#pragma unroll
      for (int r = 0; r < 4; ++r) {
        int grow = rowBase + wr * 32 + m * 16 + g * 4 + r;
        int gcol = colBase + wc * 32 + n * 16 + c;
        outf[(size_t)grow * 1024 + gcol] = acc[m][n][r] + bias[gcol];
      }
}

// ---------------- flash attention: KV tile 128 (r13, 85.4us plateau) ----------------
// No-max softmax (scores bounded: |S*log2e| <= 5.9 by l2-norm construction).
// 4 waves x 32 q-rows = 128 q/block; KV tile 128 (4 sequential 32-k subtiles).
// NOTE: no min-waves launch bound ((256,4) caused 300MB scratch spills, r6-7).
__global__ __launch_bounds__(256) void attn_fwd(
    const unsigned short* __restrict__ qn, const unsigned short* __restrict__ kn,
    const unsigned short* __restrict__ vt, const unsigned short* __restrict__ biasb,
    unsigned short* __restrict__ oup) {
  __shared__ unsigned short Ksl[2][128][72];
  __shared__ unsigned short Vsl[2][64][136];
  const int tid = threadIdx.x;
  const int lane = tid & 63;
  const int wave = tid >> 6;
  const int c5 = lane & 31;
  const int h = lane >> 5;
  const int qt = blockIdx.x;   // 16
  const int bh = blockIdx.y;   // 32
  const int b = bh >> 4, hd = bh & 15;
  const int q = qt * 128 + wave * 32 + c5;

  short8v qf[4];
  {
    const unsigned short* qp = qn + ((size_t)bh * 2048 + q) * 64 + h * 8;
#pragma unroll
    for (int kd = 0; kd < 4; ++kd) qf[kd] = *(const short8v*)(qp + kd * 16);
  }
  const unsigned short* kb = kn + (size_t)bh * 131072;
  const unsigned short* vb = vt + (size_t)bh * 131072;
  const unsigned short* bq = biasb + (size_t)q * 2048 + h * 4;

  int rk[4], ck[4], rv[4], cv[4];
#pragma unroll
  for (int i = 0; i < 4; ++i) {
    int flat = tid * 8 + i * 2048;
    rk[i] = flat >> 6;  ck[i] = flat & 63;
    rv[i] = flat >> 7;  cv[i] = flat & 127;
  }

  int4v kreg[4], vreg[4];
  u16x4 bb[4][4];

  auto ISSUE = [&](int kt) {
#pragma unroll
    for (int i = 0; i < 4; ++i) {
      kreg[i] = *(const int4v*)(kb + (size_t)(kt * 128 + rk[i]) * 64 + ck[i]);
      vreg[i] = *(const int4v*)(vb + (size_t)rv[i] * 2048 + kt * 128 + cv[i]);
    }
  };
  auto ISSUEB = [&](int n, int kt) {
#pragma unroll
    for (int Qd = 0; Qd < 4; ++Qd)
      bb[n][Qd] = *(const u16x4*)(bq + kt * 128 + n * 32 + Qd * 8);
  };
  auto WRITE = [&](int buf) {
#pragma unroll
    for (int i = 0; i < 4; ++i) {
      *(int4v*)&Ksl[buf][rk[i]][ck[i]] = kreg[i];
      *(int4v*)&Vsl[buf][rv[i]][cv[i]] = vreg[i];
    }
  };

  float l_run = 0.0f;
  f32x16 o0 = {}, o1 = {};

  ISSUE(0);
#pragma unroll
  for (int n = 0; n < 4; ++n) ISSUEB(n, 0);
  WRITE(0);
  __syncthreads();

  for (int kt = 0; kt < 16; ++kt) {
    const int cur = kt & 1;
    const bool more = (kt + 1) < 16;
    if (more) ISSUE(kt + 1);
    float rs = 0.0f;

#pragma unroll
    for (int n = 0; n < 4; ++n) {
      f32x16 s;
#pragma unroll
      for (int Qd = 0; Qd < 4; ++Qd)
#pragma unroll
        for (int r = 0; r < 4; ++r) s[Qd * 4 + r] = bf2f(bb[n][Qd][r]);
      if (more) ISSUEB(n, kt + 1);

      __builtin_amdgcn_s_setprio(1);
#pragma unroll
      for (int kd = 0; kd < 4; ++kd) {
        short8v kf = *(const short8v*)&Ksl[cur][n * 32 + c5][kd * 16 + h * 8];
        s = MFMA32(kf, qf[kd], s);
      }
      __builtin_amdgcn_s_setprio(0);

#pragma unroll
      for (int e = 0; e < 16; ++e) {
        float p = exp2_hw(s[e]);
        s[e] = p;
        rs += p;
      }

      unsigned int w[4][2];
#pragma unroll
      for (int Qd = 0; Qd < 4; ++Qd) {
        asm("v_cvt_pk_bf16_f32 %0, %1, %2"
            : "=v"(w[Qd][0]) : "v"(s[Qd * 4 + 0]), "v"(s[Qd * 4 + 1]));
        asm("v_cvt_pk_bf16_f32 %0, %1, %2"
            : "=v"(w[Qd][1]) : "v"(s[Qd * 4 + 2]), "v"(s[Qd * 4 + 3]));
      }

      __builtin_amdgcn_s_setprio(1);
#pragma unroll
      for (int kc = 0; kc < 2; ++kc) {
        unsigned int W[4];
#pragma unroll
        for (int u = 0; u < 2; ++u) {
          unsigned int A = w[kc * 2][u];
          unsigned int B = w[kc * 2 + 1][u];
          unsigned int pub = h ? A : B;
          unsigned int ex = (unsigned int)__shfl_xor((int)pub, 32);
          W[u] = h ? ex : A;
          W[2 + u] = h ? B : ex;
        }
        uint4v wv = {W[0], W[1], W[2], W[3]};
        short8v pa = __builtin_bit_cast(short8v, wv);
        short8v v0 = *(const short8v*)&Vsl[cur][c5][n * 32 + kc * 16 + h * 8];
        short8v v1 = *(const short8v*)&Vsl[cur][32 + c5][n * 32 + kc * 16 + h * 8];
        o0 = MFMA32(pa, v0, o0);
        o1 = MFMA32(pa, v1, o1);
      }
      __builtin_amdgcn_s_setprio(0);
    }

    rs += __shfl_xor(rs, 32);
    l_run += rs;

    if (more) WRITE(cur ^ 1);
    __syncthreads();
  }

  float linv = 1.0f / l_run;
#pragma unroll
  for (int e = 0; e < 16; ++e) {
    int ql = (e & 3) + 8 * (e >> 2) + 4 * h;
    float inv = __shfl(linv, ql);
    int grow = b * 2048 + qt * 128 + wave * 32 + ql;
    oup[(size_t)grow * 1024 + hd * 64 + c5] = f2bf(o0[e] * inv);
    oup[(size_t)grow * 1024 + hd * 64 + 32 + c5] = f2bf(o1[e] * inv);
  }
}

// ---------------- host launch ----------------
extern "C" void kernel_launch(void* const* d_in, const int* in_sizes, int n_in,
                              void* d_out, int out_size, void* d_ws, size_t ws_size,
                              hipStream_t stream) {
  const float* x = (const float*)d_in[0];
  const float* attn_bias = (const float*)d_in[1];
  const float* w_qkv = (const float*)d_in[2];
  const float* q_bias = (const float*)d_in[3];
  const float* v_bias = (const float*)d_in[4];
  const float* scale_mul = (const float*)d_in[5];
  const float* w_proj = (const float*)d_in[6];
  const float* b_proj = (const float*)d_in[7];
  float* out = (float*)d_out;

  char* ws = (char*)d_ws;
  unsigned short* xb = (unsigned short*)(ws);                   // [4096][1024] bf16
  unsigned short* oup = (unsigned short*)(ws);                  // alias (disjoint lifetime)
  unsigned short* wqkvb = (unsigned short*)(ws + (8 << 20));    // [3072][1024]
  unsigned short* wprojb = (unsigned short*)(ws + (14 << 20));  // [1024][1024]
  unsigned short* biasb = (unsigned short*)(ws + (16 << 20));   // [2048][2048] (*log2e)
  unsigned short* qn = (unsigned short*)(ws + (24 << 20));      // [32][2048][64]
  unsigned short* kn = (unsigned short*)(ws + (32 << 20));      // [32][2048][64]
  unsigned short* vt = (unsigned short*)(ws + (40 << 20));      // [32][64][2048]

  cast_all<<<12288, 256, 0, stream>>>(x, w_qkv, w_proj, attn_bias, xb, wqkvb,
                                      wprojb, biasb);
  gemm_qkv<<<dim3(16, 12), 512, 0, stream>>>(xb, wqkvb, qn, kn, vt, q_bias,
                                             v_bias, scale_mul);
  attn_fwd<<<dim3(16, 32), 256, 0, stream>>>(qn, kn, vt, biasb, oup);
  gemm_proj<<<dim3(64, 16), 256, 0, stream>>>(oup, wprojb, out, b_proj);
}

// Round 19
// 149.128 us; speedup vs baseline: 1.1208x; 1.0770x over previous
//
#include <hip/hip_runtime.h>

typedef __attribute__((ext_vector_type(8))) short short8v;
typedef __attribute__((ext_vector_type(4))) float f32x4;
typedef __attribute__((ext_vector_type(16))) float f32x16;
typedef __attribute__((ext_vector_type(4))) int int4v;
typedef __attribute__((ext_vector_type(4))) unsigned int uint4v;
typedef __attribute__((ext_vector_type(4))) unsigned short u16x4;

#define MFMA16(a, b, c) __builtin_amdgcn_mfma_f32_16x16x32_bf16(a, b, c, 0, 0, 0)
#define MFMA32(a, b, c) __builtin_amdgcn_mfma_f32_32x32x16_bf16(a, b, c, 0, 0, 0)

__device__ __forceinline__ unsigned short f2bf(float f) {
  unsigned int u = __builtin_bit_cast(unsigned int, f);
  return (unsigned short)((u + 0x7FFFu + ((u >> 16) & 1u)) >> 16);
}
__device__ __forceinline__ float bf2f(unsigned short s) {
  return __builtin_bit_cast(float, (unsigned int)s << 16);
}
__device__ __forceinline__ float exp2_hw(float x) {
  float r;
  asm("v_exp_f32 %0, %1" : "=v"(r) : "v"(x));
  return r;
}
// async global->LDS, 16B/lane; lds base wave-uniform (HW adds lane*16)
__device__ __forceinline__ void gl_lds16(const unsigned short* g, unsigned short* l) {
  __builtin_amdgcn_global_load_lds(
      (const __attribute__((address_space(1))) void*)g,
      (__attribute__((address_space(3))) void*)l, 16, 0, 0);
}

// ---------------- fp32->bf16 casts for x, w_qkv, w_proj (one launch) ----------------
__global__ __launch_bounds__(256) void cast_all(
    const float* __restrict__ x, const float* __restrict__ wqkv,
    const float* __restrict__ wproj,
    unsigned short* __restrict__ xb, unsigned short* __restrict__ wqkvb,
    unsigned short* __restrict__ wprojb) {
  int i = blockIdx.x * 256 + threadIdx.x;  // 0 .. 2097151 (units of 4 floats)
  const float* src;
  unsigned short* dst;
  int off;
  if (i < 1048576) { src = x; dst = xb; off = i; }
  else if (i < 1835008) { src = wqkv; dst = wqkvb; off = i - 1048576; }
  else { src = wproj; dst = wprojb; off = i - 1835008; }
  f32x4 v = *(const f32x4*)(src + (size_t)off * 4);
  u16x4 o;
#pragma unroll
  for (int j = 0; j < 4; ++j) o[j] = f2bf(v[j]);
  *(u16x4*)(dst + (size_t)off * 4) = o;
}

// ---------------- bias pack: attn_bias [q][k] fp32 -> fragment-ordered bf16 ----
// B2[plane][q][e], plane = (kt*4+n)*2+h (128 planes), e = Qd*4+r.
// Element (plane,q,e) = attn_bias[q][kt*128 + n*32 + 4h + 8*Qd + r] * log2(e).
// This is the exact C-fragment order of attn's swapped-QK MFMA32 (k-row of reg
// e is (e&3)+8*(e>>2)+4h), so attn's bias loads become lane-contiguous (q*16)
// instead of 4KB-stride scatters (64 cache lines per instruction).
__global__ __launch_bounds__(256) void bias_pack(const float* __restrict__ ab,
                                                 unsigned short* __restrict__ B2) {
  int gid = blockIdx.x * 256 + threadIdx.x;  // 0..262143
  int q = gid & 2047;
  int plane = gid >> 11;        // 0..127
  int h = plane & 1;
  int kn = plane >> 1;          // kt*4+n : 0..63
  const float* src = ab + (size_t)q * 2048 + kn * 32 + h * 4;
  unsigned short* dst = B2 + (size_t)plane * 32768 + q * 16;
#pragma unroll
  for (int Qd = 0; Qd < 4; ++Qd) {
    f32x4 v = *(const f32x4*)(src + Qd * 8);  // k = kn*32+4h+8Qd+{0..3}
    u16x4 o;
#pragma unroll
    for (int r = 0; r < 4; ++r) o[r] = f2bf(v[r] * 1.44269504088896f);
    *(u16x4*)(dst + Qd * 4) = o;
  }
}

// ---------------- QKV GEMM: 8-phase 256x256 + T2 LDS XOR-swizzle (r18) ----------------
__global__ __launch_bounds__(512) void gemm_qkv(
    const unsigned short* __restrict__ A, const unsigned short* __restrict__ Bm,
    unsigned short* __restrict__ qn, unsigned short* __restrict__ kn,
    unsigned short* __restrict__ vt,
    const float* __restrict__ bias_q, const float* __restrict__ bias_v,
    const float* __restrict__ scale_mul) {
  __shared__ unsigned short Al[2][16384];  // [slot][256 rows x 64 k] (32KB/slot)
  __shared__ unsigned short Bl[2][16384];
  const int tid = threadIdx.x;   // 0..511
  const int lane = tid & 63;
  const int wave = tid >> 6;     // 0..7
  const int wr = wave >> 2;      // 0..1  (row half: 128 rows)
  const int wcn = wave & 3;      // 0..3  (col quarter: 64 cols)
  const int c = lane & 15, g = lane >> 4;
  const int rowBase = blockIdx.x * 256;
  const int colBase = blockIdx.y * 256;
  const int srow = tid >> 3;                          // 0..63 within round
  const int scol = (((tid & 7) ^ (srow & 7)) * 8);    // u16 col, PRE-SWIZZLED (T21)

  auto STAGE_A = [&](int kt, int half) {
    int slot = kt & 1;
#pragma unroll
    for (int rr = 0; rr < 2; ++rr) {
      int r = half * 2 + rr;
      gl_lds16(A + (size_t)(rowBase + r * 64 + srow) * 1024 + kt * 64 + scol,
               &Al[slot][r * 4096 + wave * 512]);
    }
  };
  auto STAGE_B = [&](int kt, int half) {
    int slot = kt & 1;
#pragma unroll
    for (int rr = 0; rr < 2; ++rr) {
      int r = half * 2 + rr;
      gl_lds16(Bm + (size_t)(colBase + r * 64 + srow) * 1024 + kt * 64 + scol,
               &Bl[slot][r * 4096 + wave * 512]);
    }
  };
  auto LDA = [&](int slot, int row, int colu) -> short8v {
    return *(const short8v*)&Al[slot][row * 64 + (colu ^ ((row & 7) << 3))];
  };
  auto LDB = [&](int slot, int row, int colu) -> short8v {
    return *(const short8v*)&Bl[slot][row * 64 + (colu ^ ((row & 7) << 3))];
  };

  f32x4 acc[8][4];
#pragma unroll
  for (int m = 0; m < 8; ++m)
#pragma unroll
    for (int n = 0; n < 4; ++n) acc[m][n] = (f32x4){0.f, 0.f, 0.f, 0.f};

  short8v af[4][2];
  short8v bf[2][2];

  // prologue: stage whole tile 0 in ledger order A0,B0,B1,A1
  STAGE_A(0, 0);
  STAGE_B(0, 0);
  STAGE_B(0, 1);
  STAGE_A(0, 1);

  for (int kt = 0; kt < 16; ++kt) {
    const int slot = kt & 1;
    const bool more = (kt + 1) < 16;

    // ---- P0: quadrant (0,0) ----
    __builtin_amdgcn_s_barrier();  // b1: all waves done reading slot^1 (kt-1)
    if (more) STAGE_A(kt + 1, 0);
    if (more) asm volatile("s_waitcnt vmcnt(4)" ::: "memory");
    else      asm volatile("s_waitcnt vmcnt(2)" ::: "memory");
    __builtin_amdgcn_s_barrier();  // b2: A0,B0,B1(kt) visible block-wide
#pragma unroll
    for (int mm = 0; mm < 4; ++mm)
#pragma unroll
      for (int kk = 0; kk < 2; ++kk)
        af[mm][kk] = LDA(slot, wr * 128 + mm * 16 + c, kk * 32 + g * 8);
#pragma unroll
    for (int nn = 0; nn < 2; ++nn)
#pragma unroll
      for (int kk = 0; kk < 2; ++kk)
        bf[nn][kk] = LDB(slot, wcn * 64 + nn * 16 + c, kk * 32 + g * 8);
    __builtin_amdgcn_s_setprio(1);
#pragma unroll
    for (int mm = 0; mm < 4; ++mm)
#pragma unroll
      for (int nn = 0; nn < 2; ++nn)
#pragma unroll
        for (int kk = 0; kk < 2; ++kk)
          acc[mm][nn] = MFMA16(af[mm][kk], bf[nn][kk], acc[mm][nn]);
    __builtin_amdgcn_s_setprio(0);

    // ---- P1: quadrant (0,1) ----
    if (more) STAGE_B(kt + 1, 0);
#pragma unroll
    for (int nn = 0; nn < 2; ++nn)
#pragma unroll
      for (int kk = 0; kk < 2; ++kk)
        bf[nn][kk] = LDB(slot, wcn * 64 + (2 + nn) * 16 + c, kk * 32 + g * 8);
    __builtin_amdgcn_s_setprio(1);
#pragma unroll
    for (int mm = 0; mm < 4; ++mm)
#pragma unroll
      for (int nn = 0; nn < 2; ++nn)
#pragma unroll
        for (int kk = 0; kk < 2; ++kk)
          acc[mm][2 + nn] = MFMA16(af[mm][kk], bf[nn][kk], acc[mm][2 + nn]);
    __builtin_amdgcn_s_setprio(0);

    // ---- P2: quadrant (1,1) ----
    if (more) STAGE_B(kt + 1, 1);
    if (more) asm volatile("s_waitcnt vmcnt(6)" ::: "memory");
    else      asm volatile("s_waitcnt vmcnt(0)" ::: "memory");
    __builtin_amdgcn_s_barrier();  // b3: A1(kt) visible block-wide
#pragma unroll
    for (int mm = 0; mm < 4; ++mm)
#pragma unroll
      for (int kk = 0; kk < 2; ++kk)
        af[mm][kk] = LDA(slot, wr * 128 + (4 + mm) * 16 + c, kk * 32 + g * 8);
    __builtin_amdgcn_s_setprio(1);
#pragma unroll
    for (int mm = 0; mm < 4; ++mm)
#pragma unroll
      for (int nn = 0; nn < 2; ++nn)
#pragma unroll
        for (int kk = 0; kk < 2; ++kk)
          acc[4 + mm][2 + nn] = MFMA16(af[mm][kk], bf[nn][kk], acc[4 + mm][2 + nn]);
    __builtin_amdgcn_s_setprio(0);

    // ---- P3: quadrant (1,0) ----
    if (more) STAGE_A(kt + 1, 1);
#pragma unroll
    for (int nn = 0; nn < 2; ++nn)
#pragma unroll
      for (int kk = 0; kk < 2; ++kk)
        bf[nn][kk] = LDB(slot, wcn * 64 + nn * 16 + c, kk * 32 + g * 8);
    __builtin_amdgcn_s_setprio(1);
#pragma unroll
    for (int mm = 0; mm < 4; ++mm)
#pragma unroll
      for (int nn = 0; nn < 2; ++nn)
#pragma unroll
        for (int kk = 0; kk < 2; ++kk)
          acc[4 + mm][nn] = MFMA16(af[mm][kk], bf[nn][kk], acc[4 + mm][nn]);
    __builtin_amdgcn_s_setprio(0);
  }

  // ---------------- epilogue ----------------
  const int sec = colBase >> 10;                   // 0=q 1=k 2=v (block-uniform)
  const int jbase = (colBase & 1023) + wcn * 64;   // head-col base (wave-uniform)
  const int headCol = jbase >> 6;
  const int bI = rowBase >> 11;
  const int bhh = bI * 16 + headCol;

  if (sec == 2) {
    // V: bias add, per-wave swizzled LDS transpose (two 64x64 sub-tiles),
    // coalesced vt [B,H,D,L] writes. Scratch aliases Al (all compute done).
    __syncthreads();
    unsigned short* tls = &Al[0][0] + wave * 4096;  // per-wave 64x64 u16
#pragma unroll
    for (int lh = 0; lh < 2; ++lh) {
      const int lbase = (rowBase & 2047) + wr * 128 + lh * 64;
#pragma unroll
      for (int mq = 0; mq < 4; ++mq)
#pragma unroll
        for (int r = 0; r < 4; ++r)
#pragma unroll
          for (int n = 0; n < 4; ++n) {
            int d = n * 16 + c;
            int ll = mq * 16 + g * 4 + r;
            tls[d * 64 + (ll ^ ((d & 7) << 3))] =
                f2bf(acc[lh * 4 + mq][n][r] + bias_v[jbase + n * 16 + c]);
          }
      // per-wave-private region: compiler lgkm ordering suffices (no barrier)
#pragma unroll
      for (int j = 0; j < 8; ++j) {
        int idx = j * 64 + lane;
        int d = idx >> 3;
        int l8 = (idx & 7) * 8;
        short8v v8 = *(const short8v*)&tls[d * 64 + (l8 ^ ((d & 7) << 3))];
        *(short8v*)(vt + ((size_t)(bhh * 64 + d)) * 2048 + lbase + l8) = v8;
      }
    }
  } else {
    float qsc = 1.0f;
    if (sec == 0)
      qsc = __expf(fminf(scale_mul[headCol], 4.605170185988091f)) * 1.44269504088896f;
#pragma unroll
    for (int m = 0; m < 8; ++m) {
#pragma unroll
      for (int r = 0; r < 4; ++r) {
        float vv[4];
#pragma unroll
        for (int n = 0; n < 4; ++n) {
          int jn = jbase + n * 16 + c;
          float bias = (sec == 0) ? bias_q[jn] : 0.0f;
          vv[n] = acc[m][n][r] + bias;
        }
        // l2-norm across the 64 d-values of this row-head (4 regs x 16 c-lanes)
        float ss = vv[0] * vv[0] + vv[1] * vv[1] + vv[2] * vv[2] + vv[3] * vv[3];
        ss += __shfl_xor(ss, 1);
        ss += __shfl_xor(ss, 2);
        ss += __shfl_xor(ss, 4);
        ss += __shfl_xor(ss, 8);
        float sc = qsc / fmaxf(sqrtf(ss), 1e-12f);
        int grow = rowBase + wr * 128 + m * 16 + g * 4 + r;
        int l = grow & 2047;
#pragma unroll
        for (int n = 0; n < 4; ++n) {
          int d = n * 16 + c;
          unsigned short o = f2bf(vv[n] * sc);
          if (sec == 0)
            qn[(bhh * 2048 + l) * 64 + d] = o;
          else
            kn[(bhh * 2048 + l) * 64 + d] = o;
        }
      }
    }
  }
}

// ---------------- proj GEMM: out = oup @ w_proj^T + b_proj (fp32 out) ----------
__global__ __launch_bounds__(256) void gemm_proj(
    const unsigned short* __restrict__ A, const unsigned short* __restrict__ Bm,
    float* __restrict__ outf, const float* __restrict__ bias) {
  __shared__ unsigned short Asl[64 * 64];   // 8KB
  __shared__ unsigned short Bsl[64 * 64];   // 8KB
  const int tid = threadIdx.x;
  const int lane = tid & 63;
  const int wave = tid >> 6;
  const int wr = wave >> 1, wc = wave & 1;
  const int c = lane & 15, g = lane >> 4;
  const int rowBase = blockIdx.x * 64;
  const int colBase = blockIdx.y * 64;
  const int srow = lane >> 3, scol = (lane & 7) * 8;

  f32x4 acc[2][2];
#pragma unroll
  for (int m = 0; m < 2; ++m)
#pragma unroll
    for (int n = 0; n < 2; ++n) acc[m][n] = (f32x4){0.f, 0.f, 0.f, 0.f};

  for (int k0 = 0; k0 < 1024; k0 += 64) {
#pragma unroll
    for (int it = 0; it < 2; ++it) {
      int ci = wave * 2 + it;
      int r = ci * 8 + srow;
      gl_lds16(A + (size_t)(rowBase + r) * 1024 + k0 + scol, &Asl[ci * 512]);
      gl_lds16(Bm + (size_t)(colBase + r) * 1024 + k0 + scol, &Bsl[ci * 512]);
    }
    __syncthreads();
#pragma unroll
    for (int kk = 0; kk < 2; ++kk) {
      short8v af[2], bfr[2];
#pragma unroll
      for (int m = 0; m < 2; ++m)
        af[m] = *(const short8v*)&Asl[(wr * 32 + m * 16 + c) * 64 + kk * 32 + g * 8];
#pragma unroll
      for (int n = 0; n < 2; ++n)
        bfr[n] = *(const short8v*)&Bsl[(wc * 32 + n * 16 + c) * 64 + kk * 32 + g * 8];
#pragma unroll
      for (int m = 0; m < 2; ++m)
#pragma unroll
        for (int n = 0; n < 2; ++n) acc[m][n] = MFMA16(af[m], bfr[n], acc[m][n]);
    }
    __syncthreads();
  }

#pragma unroll
  for (int m = 0; m < 2; ++m)
#pragma unroll
    for (int n = 0; n < 2; ++n)
#pragma unroll
      for (int r = 0; r < 4; ++r) {
        int grow = rowBase + wr * 32 + m * 16 + g * 4 + r;
        int gcol = colBase + wc * 32 + n * 16 + c;
        outf[(size_t)grow * 1024 + gcol] = acc[m][n][r] + bias[gcol];
      }
}

// ---------------- flash attention: KV tile 128 + fragment-packed bias ----------------
// No-max softmax (scores bounded: |S*log2e| <= 5.9 by l2-norm construction).
// 4 waves x 32 q-rows = 128 q/block; KV tile 128 (4 sequential 32-k subtiles).
// Bias now read from B2[plane][q][e] (bias_pack) -> lane-contiguous loads.
// NOTE: no min-waves launch bound ((256,4) caused 300MB scratch spills, r6-7).
__global__ __launch_bounds__(256) void attn_fwd(
    const unsigned short* __restrict__ qn, const unsigned short* __restrict__ kn,
    const unsigned short* __restrict__ vt, const unsigned short* __restrict__ biasb,
    unsigned short* __restrict__ oup) {
  __shared__ unsigned short Ksl[2][128][72];
  __shared__ unsigned short Vsl[2][64][136];
  const int tid = threadIdx.x;
  const int lane = tid & 63;
  const int wave = tid >> 6;
  const int c5 = lane & 31;
  const int h = lane >> 5;
  const int qt = blockIdx.x;   // 16
  const int bh = blockIdx.y;   // 32
  const int b = bh >> 4, hd = bh & 15;
  const int q = qt * 128 + wave * 32 + c5;

  short8v qf[4];
  {
    const unsigned short* qp = qn + ((size_t)bh * 2048 + q) * 64 + h * 8;
#pragma unroll
    for (int kd = 0; kd < 4; ++kd) qf[kd] = *(const short8v*)(qp + kd * 16);
  }
  const unsigned short* kb = kn + (size_t)bh * 131072;
  const unsigned short* vb = vt + (size_t)bh * 131072;
  // fragment-packed bias base for this lane: B2[plane][q][e], plane=(kt*4+n)*2+h
  const unsigned short* bq = biasb + (size_t)q * 16 + (size_t)h * 32768;

  int rk[4], ck[4], rv[4], cv[4];
#pragma unroll
  for (int i = 0; i < 4; ++i) {
    int flat = tid * 8 + i * 2048;
    rk[i] = flat >> 6;  ck[i] = flat & 63;
    rv[i] = flat >> 7;  cv[i] = flat & 127;
  }

  int4v kreg[4], vreg[4];
  u16x4 bb[4][4];

  auto ISSUE = [&](int kt) {
#pragma unroll
    for (int i = 0; i < 4; ++i) {
      kreg[i] = *(const int4v*)(kb + (size_t)(kt * 128 + rk[i]) * 64 + ck[i]);
      vreg[i] = *(const int4v*)(vb + (size_t)rv[i] * 2048 + kt * 128 + cv[i]);
    }
  };
  auto ISSUEB = [&](int n, int kt) {
    const unsigned short* p = bq + (size_t)(kt * 4 + n) * 65536;  // *2 planes*32768
#pragma unroll
    for (int Qd = 0; Qd < 4; ++Qd)
      bb[n][Qd] = *(const u16x4*)(p + Qd * 4);
  };
  auto WRITE = [&](int buf) {
#pragma unroll
    for (int i = 0; i < 4; ++i) {
      *(int4v*)&Ksl[buf][rk[i]][ck[i]] = kreg[i];
      *(int4v*)&Vsl[buf][rv[i]][cv[i]] = vreg[i];
    }
  };

  float l_run = 0.0f;
  f32x16 o0 = {}, o1 = {};

  ISSUE(0);
#pragma unroll
  for (int n = 0; n < 4; ++n) ISSUEB(n, 0);
  WRITE(0);
  __syncthreads();

  for (int kt = 0; kt < 16; ++kt) {
    const int cur = kt & 1;
    const bool more = (kt + 1) < 16;
    if (more) ISSUE(kt + 1);
    float rs = 0.0f;

#pragma unroll
    for (int n = 0; n < 4; ++n) {
      f32x16 s;
#pragma unroll
      for (int Qd = 0; Qd < 4; ++Qd)
#pragma unroll
        for (int r = 0; r < 4; ++r) s[Qd * 4 + r] = bf2f(bb[n][Qd][r]);
      if (more) ISSUEB(n, kt + 1);

      __builtin_amdgcn_s_setprio(1);
#pragma unroll
      for (int kd = 0; kd < 4; ++kd) {
        short8v kf = *(const short8v*)&Ksl[cur][n * 32 + c5][kd * 16 + h * 8];
        s = MFMA32(kf, qf[kd], s);
      }
      __builtin_amdgcn_s_setprio(0);

#pragma unroll
      for (int e = 0; e < 16; ++e) {
        float p = exp2_hw(s[e]);
        s[e] = p;
        rs += p;
      }

      unsigned int w[4][2];
#pragma unroll
      for (int Qd = 0; Qd < 4; ++Qd) {
        asm("v_cvt_pk_bf16_f32 %0, %1, %2"
            : "=v"(w[Qd][0]) : "v"(s[Qd * 4 + 0]), "v"(s[Qd * 4 + 1]));
        asm("v_cvt_pk_bf16_f32 %0, %1, %2"
            : "=v"(w[Qd][1]) : "v"(s[Qd * 4 + 2]), "v"(s[Qd * 4 + 3]));
      }

      __builtin_amdgcn_s_setprio(1);
#pragma unroll
      for (int kc = 0; kc < 2; ++kc) {
        unsigned int W[4];
#pragma unroll
        for (int u = 0; u < 2; ++u) {
          unsigned int A = w[kc * 2][u];
          unsigned int B = w[kc * 2 + 1][u];
          unsigned int pub = h ? A : B;
          unsigned int ex = (unsigned int)__shfl_xor((int)pub, 32);
          W[u] = h ? ex : A;
          W[2 + u] = h ? B : ex;
        }
        uint4v wv = {W[0], W[1], W[2], W[3]};
        short8v pa = __builtin_bit_cast(short8v, wv);
        short8v v0 = *(const short8v*)&Vsl[cur][c5][n * 32 + kc * 16 + h * 8];
        short8v v1 = *(const short8v*)&Vsl[cur][32 + c5][n * 32 + kc * 16 + h * 8];
        o0 = MFMA32(pa, v0, o0);
        o1 = MFMA32(pa, v1, o1);
      }
      __builtin_amdgcn_s_setprio(0);
    }

    rs += __shfl_xor(rs, 32);
    l_run += rs;

    if (more) WRITE(cur ^ 1);
    __syncthreads();
  }

  float linv = 1.0f / l_run;
#pragma unroll
  for (int e = 0; e < 16; ++e) {
    int ql = (e & 3) + 8 * (e >> 2) + 4 * h;
    float inv = __shfl(linv, ql);
    int grow = b * 2048 + qt * 128 + wave * 32 + ql;
    oup[(size_t)grow * 1024 + hd * 64 + c5] = f2bf(o0[e] * inv);
    oup[(size_t)grow * 1024 + hd * 64 + 32 + c5] = f2bf(o1[e] * inv);
  }
}

// ---------------- host launch ----------------
extern "C" void kernel_launch(void* const* d_in, const int* in_sizes, int n_in,
                              void* d_out, int out_size, void* d_ws, size_t ws_size,
                              hipStream_t stream) {
  const float* x = (const float*)d_in[0];
  const float* attn_bias = (const float*)d_in[1];
  const float* w_qkv = (const float*)d_in[2];
  const float* q_bias = (const float*)d_in[3];
  const float* v_bias = (const float*)d_in[4];
  const float* scale_mul = (const float*)d_in[5];
  const float* w_proj = (const float*)d_in[6];
  const float* b_proj = (const float*)d_in[7];
  float* out = (float*)d_out;

  char* ws = (char*)d_ws;
  unsigned short* xb = (unsigned short*)(ws);                   // [4096][1024] bf16
  unsigned short* oup = (unsigned short*)(ws);                  // alias (disjoint lifetime)
  unsigned short* wqkvb = (unsigned short*)(ws + (8 << 20));    // [3072][1024]
  unsigned short* wprojb = (unsigned short*)(ws + (14 << 20));  // [1024][1024]
  unsigned short* biasb = (unsigned short*)(ws + (16 << 20));   // B2 [128][2048][16] (*log2e)
  unsigned short* qn = (unsigned short*)(ws + (24 << 20));      // [32][2048][64]
  unsigned short* kn = (unsigned short*)(ws + (32 << 20));      // [32][2048][64]
  unsigned short* vt = (unsigned short*)(ws + (40 << 20));      // [32][64][2048]

  cast_all<<<8192, 256, 0, stream>>>(x, w_qkv, w_proj, xb, wqkvb, wprojb);
  bias_pack<<<1024, 256, 0, stream>>>(attn_bias, biasb);
  gemm_qkv<<<dim3(16, 12), 512, 0, stream>>>(xb, wqkvb, qn, kn, vt, q_bias,
                                             v_bias, scale_mul);
  attn_fwd<<<dim3(16, 32), 256, 0, stream>>>(qn, kn, vt, biasb, oup);
  gemm_proj<<<dim3(64, 16), 256, 0, stream>>>(oup, wprojb, out, b_proj);
}

// Round 20
// 148.103 us; speedup vs baseline: 1.1285x; 1.0069x over previous
//
#include <hip/hip_runtime.h>

typedef __attribute__((ext_vector_type(8))) short short8v;
typedef __attribute__((ext_vector_type(4))) float f32x4;
typedef __attribute__((ext_vector_type(16))) float f32x16;
typedef __attribute__((ext_vector_type(4))) int int4v;
typedef __attribute__((ext_vector_type(4))) unsigned int uint4v;
typedef __attribute__((ext_vector_type(4))) unsigned short u16x4;

#define MFMA16(a, b, c) __builtin_amdgcn_mfma_f32_16x16x32_bf16(a, b, c, 0, 0, 0)
#define MFMA32(a, b, c) __builtin_amdgcn_mfma_f32_32x32x16_bf16(a, b, c, 0, 0, 0)

__device__ __forceinline__ unsigned short f2bf(float f) {
  unsigned int u = __builtin_bit_cast(unsigned int, f);
  return (unsigned short)((u + 0x7FFFu + ((u >> 16) & 1u)) >> 16);
}
__device__ __forceinline__ float bf2f(unsigned short s) {
  return __builtin_bit_cast(float, (unsigned int)s << 16);
}
__device__ __forceinline__ float exp2_hw(float x) {
  float r;
  asm("v_exp_f32 %0, %1" : "=v"(r) : "v"(x));
  return r;
}
// async global->LDS, 16B/lane; lds base wave-uniform (HW adds lane*16)
__device__ __forceinline__ void gl_lds16(const unsigned short* g, unsigned short* l) {
  __builtin_amdgcn_global_load_lds(
      (const __attribute__((address_space(1))) void*)g,
      (__attribute__((address_space(3))) void*)l, 16, 0, 0);
}

// ---------------- fused prep: fp32->bf16 casts + fragment-ordered bias pack ----
// jobs 0..2097151: cast x/wqkv/wproj (4 floats each).
// jobs 2097152..2359295: bias_pack — B2[plane][q][e] bf16 (*log2e), plane =
// (kt*4+n)*2+h, e = Qd*4+r; element = attn_bias[q][kn*32 + 4h + 8Qd + r].
// Fragment order matches attn's swapped-QK MFMA32 C-layout (k-row of reg e is
// (e&3)+8*(e>>2)+4h) -> attn bias loads are lane-contiguous (q*16), not 4KB-
// stride scatters (r19: -19us on attn).
__global__ __launch_bounds__(256) void prep_all(
    const float* __restrict__ x, const float* __restrict__ wqkv,
    const float* __restrict__ wproj, const float* __restrict__ ab,
    unsigned short* __restrict__ xb, unsigned short* __restrict__ wqkvb,
    unsigned short* __restrict__ wprojb, unsigned short* __restrict__ B2) {
  int i = blockIdx.x * 256 + threadIdx.x;  // 0 .. 2359295
  if (i < 2097152) {
    const float* src;
    unsigned short* dst;
    int off;
    if (i < 1048576) { src = x; dst = xb; off = i; }
    else if (i < 1835008) { src = wqkv; dst = wqkvb; off = i - 1048576; }
    else { src = wproj; dst = wprojb; off = i - 1835008; }
    f32x4 v = *(const f32x4*)(src + (size_t)off * 4);
    u16x4 o;
#pragma unroll
    for (int j = 0; j < 4; ++j) o[j] = f2bf(v[j]);
    *(u16x4*)(dst + (size_t)off * 4) = o;
  } else {
    int gid = i - 2097152;        // 0..262143
    int q = gid & 2047;
    int plane = gid >> 11;        // 0..127
    int h = plane & 1;
    int kn = plane >> 1;          // kt*4+n : 0..63
    const float* src = ab + (size_t)q * 2048 + kn * 32 + h * 4;
    unsigned short* dst = B2 + (size_t)plane * 32768 + q * 16;
#pragma unroll
    for (int Qd = 0; Qd < 4; ++Qd) {
      f32x4 v = *(const f32x4*)(src + Qd * 8);  // k = kn*32+4h+8Qd+{0..3}
      u16x4 o;
#pragma unroll
      for (int r = 0; r < 4; ++r) o[r] = f2bf(v[r] * 1.44269504088896f);
      *(u16x4*)(dst + Qd * 4) = o;
    }
  }
}

// ---------------- QKV GEMM: 8-phase 256x256 + T2 LDS XOR-swizzle (r18) ----------------
__global__ __launch_bounds__(512) void gemm_qkv(
    const unsigned short* __restrict__ A, const unsigned short* __restrict__ Bm,
    unsigned short* __restrict__ qn, unsigned short* __restrict__ kn,
    unsigned short* __restrict__ vt,
    const float* __restrict__ bias_q, const float* __restrict__ bias_v,
    const float* __restrict__ scale_mul) {
  __shared__ unsigned short Al[2][16384];  // [slot][256 rows x 64 k] (32KB/slot)
  __shared__ unsigned short Bl[2][16384];
  const int tid = threadIdx.x;   // 0..511
  const int lane = tid & 63;
  const int wave = tid >> 6;     // 0..7
  const int wr = wave >> 2;      // 0..1  (row half: 128 rows)
  const int wcn = wave & 3;      // 0..3  (col quarter: 64 cols)
  const int c = lane & 15, g = lane >> 4;
  const int rowBase = blockIdx.x * 256;
  const int colBase = blockIdx.y * 256;
  const int srow = tid >> 3;                          // 0..63 within round
  const int scol = (((tid & 7) ^ (srow & 7)) * 8);    // u16 col, PRE-SWIZZLED (T21)

  auto STAGE_A = [&](int kt, int half) {
    int slot = kt & 1;
#pragma unroll
    for (int rr = 0; rr < 2; ++rr) {
      int r = half * 2 + rr;
      gl_lds16(A + (size_t)(rowBase + r * 64 + srow) * 1024 + kt * 64 + scol,
               &Al[slot][r * 4096 + wave * 512]);
    }
  };
  auto STAGE_B = [&](int kt, int half) {
    int slot = kt & 1;
#pragma unroll
    for (int rr = 0; rr < 2; ++rr) {
      int r = half * 2 + rr;
      gl_lds16(Bm + (size_t)(colBase + r * 64 + srow) * 1024 + kt * 64 + scol,
               &Bl[slot][r * 4096 + wave * 512]);
    }
  };
  auto LDA = [&](int slot, int row, int colu) -> short8v {
    return *(const short8v*)&Al[slot][row * 64 + (colu ^ ((row & 7) << 3))];
  };
  auto LDB = [&](int slot, int row, int colu) -> short8v {
    return *(const short8v*)&Bl[slot][row * 64 + (colu ^ ((row & 7) << 3))];
  };

  f32x4 acc[8][4];
#pragma unroll
  for (int m = 0; m < 8; ++m)
#pragma unroll
    for (int n = 0; n < 4; ++n) acc[m][n] = (f32x4){0.f, 0.f, 0.f, 0.f};

  short8v af[4][2];
  short8v bf[2][2];

  // prologue: stage whole tile 0 in ledger order A0,B0,B1,A1
  STAGE_A(0, 0);
  STAGE_B(0, 0);
  STAGE_B(0, 1);
  STAGE_A(0, 1);

  for (int kt = 0; kt < 16; ++kt) {
    const int slot = kt & 1;
    const bool more = (kt + 1) < 16;

    // ---- P0: quadrant (0,0) ----
    __builtin_amdgcn_s_barrier();  // b1: all waves done reading slot^1 (kt-1)
    if (more) STAGE_A(kt + 1, 0);
    if (more) asm volatile("s_waitcnt vmcnt(4)" ::: "memory");
    else      asm volatile("s_waitcnt vmcnt(2)" ::: "memory");
    __builtin_amdgcn_s_barrier();  // b2: A0,B0,B1(kt) visible block-wide
#pragma unroll
    for (int mm = 0; mm < 4; ++mm)
#pragma unroll
      for (int kk = 0; kk < 2; ++kk)
        af[mm][kk] = LDA(slot, wr * 128 + mm * 16 + c, kk * 32 + g * 8);
#pragma unroll
    for (int nn = 0; nn < 2; ++nn)
#pragma unroll
      for (int kk = 0; kk < 2; ++kk)
        bf[nn][kk] = LDB(slot, wcn * 64 + nn * 16 + c, kk * 32 + g * 8);
    __builtin_amdgcn_s_setprio(1);
#pragma unroll
    for (int mm = 0; mm < 4; ++mm)
#pragma unroll
      for (int nn = 0; nn < 2; ++nn)
#pragma unroll
        for (int kk = 0; kk < 2; ++kk)
          acc[mm][nn] = MFMA16(af[mm][kk], bf[nn][kk], acc[mm][nn]);
    __builtin_amdgcn_s_setprio(0);

    // ---- P1: quadrant (0,1) ----
    if (more) STAGE_B(kt + 1, 0);
#pragma unroll
    for (int nn = 0; nn < 2; ++nn)
#pragma unroll
      for (int kk = 0; kk < 2; ++kk)
        bf[nn][kk] = LDB(slot, wcn * 64 + (2 + nn) * 16 + c, kk * 32 + g * 8);
    __builtin_amdgcn_s_setprio(1);
#pragma unroll
    for (int mm = 0; mm < 4; ++mm)
#pragma unroll
      for (int nn = 0; nn < 2; ++nn)
#pragma unroll
        for (int kk = 0; kk < 2; ++kk)
          acc[mm][2 + nn] = MFMA16(af[mm][kk], bf[nn][kk], acc[mm][2 + nn]);
    __builtin_amdgcn_s_setprio(0);

    // ---- P2: quadrant (1,1) ----
    if (more) STAGE_B(kt + 1, 1);
    if (more) asm volatile("s_waitcnt vmcnt(6)" ::: "memory");
    else      asm volatile("s_waitcnt vmcnt(0)" ::: "memory");
    __builtin_amdgcn_s_barrier();  // b3: A1(kt) visible block-wide
#pragma unroll
    for (int mm = 0; mm < 4; ++mm)
#pragma unroll
      for (int kk = 0; kk < 2; ++kk)
        af[mm][kk] = LDA(slot, wr * 128 + (4 + mm) * 16 + c, kk * 32 + g * 8);
    __builtin_amdgcn_s_setprio(1);
#pragma unroll
    for (int mm = 0; mm < 4; ++mm)
#pragma unroll
      for (int nn = 0; nn < 2; ++nn)
#pragma unroll
        for (int kk = 0; kk < 2; ++kk)
          acc[4 + mm][2 + nn] = MFMA16(af[mm][kk], bf[nn][kk], acc[4 + mm][2 + nn]);
    __builtin_amdgcn_s_setprio(0);

    // ---- P3: quadrant (1,0) ----
    if (more) STAGE_A(kt + 1, 1);
#pragma unroll
    for (int nn = 0; nn < 2; ++nn)
#pragma unroll
      for (int kk = 0; kk < 2; ++kk)
        bf[nn][kk] = LDB(slot, wcn * 64 + nn * 16 + c, kk * 32 + g * 8);
    __builtin_amdgcn_s_setprio(1);
#pragma unroll
    for (int mm = 0; mm < 4; ++mm)
#pragma unroll
      for (int nn = 0; nn < 2; ++nn)
#pragma unroll
        for (int kk = 0; kk < 2; ++kk)
          acc[4 + mm][nn] = MFMA16(af[mm][kk], bf[nn][kk], acc[4 + mm][nn]);
    __builtin_amdgcn_s_setprio(0);
  }

  // ---------------- epilogue ----------------
  const int sec = colBase >> 10;                   // 0=q 1=k 2=v (block-uniform)
  const int jbase = (colBase & 1023) + wcn * 64;   // head-col base (wave-uniform)
  const int headCol = jbase >> 6;
  const int bI = rowBase >> 11;
  const int bhh = bI * 16 + headCol;

  if (sec == 2) {
    // V: bias add, per-wave swizzled LDS transpose (two 64x64 sub-tiles),
    // coalesced vt [B,H,D,L] writes. Scratch aliases Al (all compute done).
    __syncthreads();
    unsigned short* tls = &Al[0][0] + wave * 4096;  // per-wave 64x64 u16
#pragma unroll
    for (int lh = 0; lh < 2; ++lh) {
      const int lbase = (rowBase & 2047) + wr * 128 + lh * 64;
#pragma unroll
      for (int mq = 0; mq < 4; ++mq)
#pragma unroll
        for (int r = 0; r < 4; ++r)
#pragma unroll
          for (int n = 0; n < 4; ++n) {
            int d = n * 16 + c;
            int ll = mq * 16 + g * 4 + r;
            tls[d * 64 + (ll ^ ((d & 7) << 3))] =
                f2bf(acc[lh * 4 + mq][n][r] + bias_v[jbase + n * 16 + c]);
          }
      // per-wave-private region: compiler lgkm ordering suffices (no barrier)
#pragma unroll
      for (int j = 0; j < 8; ++j) {
        int idx = j * 64 + lane;
        int d = idx >> 3;
        int l8 = (idx & 7) * 8;
        short8v v8 = *(const short8v*)&tls[d * 64 + (l8 ^ ((d & 7) << 3))];
        *(short8v*)(vt + ((size_t)(bhh * 64 + d)) * 2048 + lbase + l8) = v8;
      }
    }
  } else {
    float qsc = 1.0f;
    if (sec == 0)
      qsc = __expf(fminf(scale_mul[headCol], 4.605170185988091f)) * 1.44269504088896f;
#pragma unroll
    for (int m = 0; m < 8; ++m) {
#pragma unroll
      for (int r = 0; r < 4; ++r) {
        float vv[4];
#pragma unroll
        for (int n = 0; n < 4; ++n) {
          int jn = jbase + n * 16 + c;
          float bias = (sec == 0) ? bias_q[jn] : 0.0f;
          vv[n] = acc[m][n][r] + bias;
        }
        // l2-norm across the 64 d-values of this row-head (4 regs x 16 c-lanes)
        float ss = vv[0] * vv[0] + vv[1] * vv[1] + vv[2] * vv[2] + vv[3] * vv[3];
        ss += __shfl_xor(ss, 1);
        ss += __shfl_xor(ss, 2);
        ss += __shfl_xor(ss, 4);
        ss += __shfl_xor(ss, 8);
        float sc = qsc / fmaxf(sqrtf(ss), 1e-12f);
        int grow = rowBase + wr * 128 + m * 16 + g * 4 + r;
        int l = grow & 2047;
#pragma unroll
        for (int n = 0; n < 4; ++n) {
          int d = n * 16 + c;
          unsigned short o = f2bf(vv[n] * sc);
          if (sec == 0)
            qn[(bhh * 2048 + l) * 64 + d] = o;
          else
            kn[(bhh * 2048 + l) * 64 + d] = o;
        }
      }
    }
  }
}

// ---------------- proj GEMM: out = oup @ w_proj^T + b_proj (fp32 out) ----------
__global__ __launch_bounds__(256) void gemm_proj(
    const unsigned short* __restrict__ A, const unsigned short* __restrict__ Bm,
    float* __restrict__ outf, const float* __restrict__ bias) {
  __shared__ unsigned short Asl[64 * 64];   // 8KB
  __shared__ unsigned short Bsl[64 * 64];   // 8KB
  const int tid = threadIdx.x;
  const int lane = tid & 63;
  const int wave = tid >> 6;
  const int wr = wave >> 1, wc = wave & 1;
  const int c = lane & 15, g = lane >> 4;
  const int rowBase = blockIdx.x * 64;
  const int colBase = blockIdx.y * 64;
  const int srow = lane >> 3, scol = (lane & 7) * 8;

  f32x4 acc[2][2];
#pragma unroll
  for (int m = 0; m < 2; ++m)
#pragma unroll
    for (int n = 0; n < 2; ++n) acc[m][n] = (f32x4){0.f, 0.f, 0.f, 0.f};

  for (int k0 = 0; k0 < 1024; k0 += 64) {
#pragma unroll
    for (int it = 0; it < 2; ++it) {
      int ci = wave * 2 + it;
      int r = ci * 8 + srow;
      gl_lds16(A + (size_t)(rowBase + r) * 1024 + k0 + scol, &Asl[ci * 512]);
      gl_lds16(Bm + (size_t)(colBase + r) * 1024 + k0 + scol, &Bsl[ci * 512]);
    }
    __syncthreads();
#pragma unroll
    for (int kk = 0; kk < 2; ++kk) {
      short8v af[2], bfr[2];
#pragma unroll
      for (int m = 0; m < 2; ++m)
        af[m] = *(const short8v*)&Asl[(wr * 32 + m * 16 + c) * 64 + kk * 32 + g * 8];
#pragma unroll
      for (int n = 0; n < 2; ++n)
        bfr[n] = *(const short8v*)&Bsl[(wc * 32 + n * 16 + c) * 64 + kk * 32 + g * 8];
#pragma unroll
      for (int m = 0; m < 2; ++m)
#pragma unroll
        for (int n = 0; n < 2; ++n) acc[m][n] = MFMA16(af[m], bfr[n], acc[m][n]);
    }
    __syncthreads();
  }

#pragma unroll
  for (int m = 0; m < 2; ++m)
#pragma unroll
    for (int n = 0; n < 2; ++n)
#pragma unroll
      for (int r = 0; r < 4; ++r) {
        int grow = rowBase + wr * 32 + m * 16 + g * 4 + r;
        int gcol = colBase + wc * 32 + n * 16 + c;
        outf[(size_t)grow * 1024 + gcol] = acc[m][n][r] + bias[gcol];
      }
}

// ---------------- flash attention: KV tile 128 + fragment-packed bias (r19) ----------
// No-max softmax (scores bounded: |S*log2e| <= 5.9 by l2-norm construction).
// 4 waves x 32 q-rows = 128 q/block; KV tile 128 (4 sequential 32-k subtiles).
// Bias read from B2[plane][q][e] -> lane-contiguous loads (r19: -19us).
// NOTE: no min-waves launch bound ((256,4) caused 300MB scratch spills, r6-7).
__global__ __launch_bounds__(256) void attn_fwd(
    const unsigned short* __restrict__ qn, const unsigned short* __restrict__ kn,
    const unsigned short* __restrict__ vt, const unsigned short* __restrict__ biasb,
    unsigned short* __restrict__ oup) {
  __shared__ unsigned short Ksl[2][128][72];
  __shared__ unsigned short Vsl[2][64][136];
  const int tid = threadIdx.x;
  const int lane = tid & 63;
  const int wave = tid >> 6;
  const int c5 = lane & 31;
  const int h = lane >> 5;
  const int qt = blockIdx.x;   // 16
  const int bh = blockIdx.y;   // 32
  const int b = bh >> 4, hd = bh & 15;
  const int q = qt * 128 + wave * 32 + c5;

  short8v qf[4];
  {
    const unsigned short* qp = qn + ((size_t)bh * 2048 + q) * 64 + h * 8;
#pragma unroll
    for (int kd = 0; kd < 4; ++kd) qf[kd] = *(const short8v*)(qp + kd * 16);
  }
  const unsigned short* kb = kn + (size_t)bh * 131072;
  const unsigned short* vb = vt + (size_t)bh * 131072;
  // fragment-packed bias base for this lane: B2[plane][q][e], plane=(kt*4+n)*2+h
  const unsigned short* bq = biasb + (size_t)q * 16 + (size_t)h * 32768;

  int rk[4], ck[4], rv[4], cv[4];
#pragma unroll
  for (int i = 0; i < 4; ++i) {
    int flat = tid * 8 + i * 2048;
    rk[i] = flat >> 6;  ck[i] = flat & 63;
    rv[i] = flat >> 7;  cv[i] = flat & 127;
  }

  int4v kreg[4], vreg[4];
  u16x4 bb[4][4];

  auto ISSUE = [&](int kt) {
#pragma unroll
    for (int i = 0; i < 4; ++i) {
      kreg[i] = *(const int4v*)(kb + (size_t)(kt * 128 + rk[i]) * 64 + ck[i]);
      vreg[i] = *(const int4v*)(vb + (size_t)rv[i] * 2048 + kt * 128 + cv[i]);
    }
  };
  auto ISSUEB = [&](int n, int kt) {
    const unsigned short* p = bq + (size_t)(kt * 4 + n) * 65536;  // *2 planes*32768
#pragma unroll
    for (int Qd = 0; Qd < 4; ++Qd)
      bb[n][Qd] = *(const u16x4*)(p + Qd * 4);
  };
  auto WRITE = [&](int buf) {
#pragma unroll
    for (int i = 0; i < 4; ++i) {
      *(int4v*)&Ksl[buf][rk[i]][ck[i]] = kreg[i];
      *(int4v*)&Vsl[buf][rv[i]][cv[i]] = vreg[i];
    }
  };

  float l_run = 0.0f;
  f32x16 o0 = {}, o1 = {};

  ISSUE(0);
#pragma unroll
  for (int n = 0; n < 4; ++n) ISSUEB(n, 0);
  WRITE(0);
  __syncthreads();

  for (int kt = 0; kt < 16; ++kt) {
    const int cur = kt & 1;
    const bool more = (kt + 1) < 16;
    if (more) ISSUE(kt + 1);
    float rs = 0.0f;

#pragma unroll
    for (int n = 0; n < 4; ++n) {
      f32x16 s;
#pragma unroll
      for (int Qd = 0; Qd < 4; ++Qd)
#pragma unroll
        for (int r = 0; r < 4; ++r) s[Qd * 4 + r] = bf2f(bb[n][Qd][r]);
      if (more) ISSUEB(n, kt + 1);

      __builtin_amdgcn_s_setprio(1);
#pragma unroll
      for (int kd = 0; kd < 4; ++kd) {
        short8v kf = *(const short8v*)&Ksl[cur][n * 32 + c5][kd * 16 + h * 8];
        s = MFMA32(kf, qf[kd], s);
      }
      __builtin_amdgcn_s_setprio(0);

#pragma unroll
      for (int e = 0; e < 16; ++e) {
        float p = exp2_hw(s[e]);
        s[e] = p;
        rs += p;
      }

      unsigned int w[4][2];
#pragma unroll
      for (int Qd = 0; Qd < 4; ++Qd) {
        asm("v_cvt_pk_bf16_f32 %0, %1, %2"
            : "=v"(w[Qd][0]) : "v"(s[Qd * 4 + 0]), "v"(s[Qd * 4 + 1]));
        asm("v_cvt_pk_bf16_f32 %0, %1, %2"
            : "=v"(w[Qd][1]) : "v"(s[Qd * 4 + 2]), "v"(s[Qd * 4 + 3]));
      }

      __builtin_amdgcn_s_setprio(1);
#pragma unroll
      for (int kc = 0; kc < 2; ++kc) {
        unsigned int W[4];
#pragma unroll
        for (int u = 0; u < 2; ++u) {
          unsigned int A = w[kc * 2][u];
          unsigned int B = w[kc * 2 + 1][u];
          unsigned int pub = h ? A : B;
          unsigned int ex = (unsigned int)__shfl_xor((int)pub, 32);
          W[u] = h ? ex : A;
          W[2 + u] = h ? B : ex;
        }
        uint4v wv = {W[0], W[1], W[2], W[3]};
        short8v pa = __builtin_bit_cast(short8v, wv);
        short8v v0 = *(const short8v*)&Vsl[cur][c5][n * 32 + kc * 16 + h * 8];
        short8v v1 = *(const short8v*)&Vsl[cur][32 + c5][n * 32 + kc * 16 + h * 8];
        o0 = MFMA32(pa, v0, o0);
        o1 = MFMA32(pa, v1, o1);
      }
      __builtin_amdgcn_s_setprio(0);
    }

    rs += __shfl_xor(rs, 32);
    l_run += rs;

    if (more) WRITE(cur ^ 1);
    __syncthreads();
  }

  float linv = 1.0f / l_run;
#pragma unroll
  for (int e = 0; e < 16; ++e) {
    int ql = (e & 3) + 8 * (e >> 2) + 4 * h;
    float inv = __shfl(linv, ql);
    int grow = b * 2048 + qt * 128 + wave * 32 + ql;
    oup[(size_t)grow * 1024 + hd * 64 + c5] = f2bf(o0[e] * inv);
    oup[(size_t)grow * 1024 + hd * 64 + 32 + c5] = f2bf(o1[e] * inv);
  }
}

// ---------------- host launch ----------------
extern "C" void kernel_launch(void* const* d_in, const int* in_sizes, int n_in,
                              void* d_out, int out_size, void* d_ws, size_t ws_size,
                              hipStream_t stream) {
  const float* x = (const float*)d_in[0];
  const float* attn_bias = (const float*)d_in[1];
  const float* w_qkv = (const float*)d_in[2];
  const float* q_bias = (const float*)d_in[3];
  const float* v_bias = (const float*)d_in[4];
  const float* scale_mul = (const float*)d_in[5];
  const float* w_proj = (const float*)d_in[6];
  const float* b_proj = (const float*)d_in[7];
  float* out = (float*)d_out;

  char* ws = (char*)d_ws;
  unsigned short* xb = (unsigned short*)(ws);                   // [4096][1024] bf16
  unsigned short* oup = (unsigned short*)(ws);                  // alias (disjoint lifetime)
  unsigned short* wqkvb = (unsigned short*)(ws + (8 << 20));    // [3072][1024]
  unsigned short* wprojb = (unsigned short*)(ws + (14 << 20));  // [1024][1024]
  unsigned short* biasb = (unsigned short*)(ws + (16 << 20));   // B2 [128][2048][16] (*log2e)
  unsigned short* qn = (unsigned short*)(ws + (24 << 20));      // [32][2048][64]
  unsigned short* kn = (unsigned short*)(ws + (32 << 20));      // [32][2048][64]
  unsigned short* vt = (unsigned short*)(ws + (40 << 20));      // [32][64][2048]

  prep_all<<<9216, 256, 0, stream>>>(x, w_qkv, w_proj, attn_bias, xb, wqkvb,
                                     wprojb, biasb);
  gemm_qkv<<<dim3(16, 12), 512, 0, stream>>>(xb, wqkvb, qn, kn, vt, q_bias,
                                             v_bias, scale_mul);
  attn_fwd<<<dim3(16, 32), 256, 0, stream>>>(qn, kn, vt, biasb, oup);
  gemm_proj<<<dim3(64, 16), 256, 0, stream>>>(oup, wprojb, out, b_proj);
}

// Round 21
// 145.827 us; speedup vs baseline: 1.1462x; 1.0156x over previous
//
#include <hip/hip_runtime.h>

typedef __attribute__((ext_vector_type(8))) short short8v;
typedef __attribute__((ext_vector_type(4))) float f32x4;
typedef __attribute__((ext_vector_type(16))) float f32x16;
typedef __attribute__((ext_vector_type(4))) int int4v;
typedef __attribute__((ext_vector_type(4))) unsigned int uint4v;
typedef __attribute__((ext_vector_type(4))) unsigned short u16x4;

#define MFMA16(a, b, c) __builtin_amdgcn_mfma_f32_16x16x32_bf16(a, b, c, 0, 0, 0)
#define MFMA32(a, b, c) __builtin_amdgcn_mfma_f32_32x32x16_bf16(a, b, c, 0, 0, 0)

__device__ __forceinline__ unsigned short f2bf(float f) {
  unsigned int u = __builtin_bit_cast(unsigned int, f);
  return (unsigned short)((u + 0x7FFFu + ((u >> 16) & 1u)) >> 16);
}
__device__ __forceinline__ float bf2f(unsigned short s) {
  return __builtin_bit_cast(float, (unsigned int)s << 16);
}
__device__ __forceinline__ float exp2_hw(float x) {
  float r;
  asm("v_exp_f32 %0, %1" : "=v"(r) : "v"(x));
  return r;
}
// async global->LDS, 16B/lane; lds base wave-uniform (HW adds lane*16)
__device__ __forceinline__ void gl_lds16(const unsigned short* g, unsigned short* l) {
  __builtin_amdgcn_global_load_lds(
      (const __attribute__((address_space(1))) void*)g,
      (__attribute__((address_space(3))) void*)l, 16, 0, 0);
}

// ---------------- fused prep: fp32->bf16 casts + fragment-ordered bias pack ----
__global__ __launch_bounds__(256) void prep_all(
    const float* __restrict__ x, const float* __restrict__ wqkv,
    const float* __restrict__ wproj, const float* __restrict__ ab,
    unsigned short* __restrict__ xb, unsigned short* __restrict__ wqkvb,
    unsigned short* __restrict__ wprojb, unsigned short* __restrict__ B2) {
  int i = blockIdx.x * 256 + threadIdx.x;  // 0 .. 2359295
  if (i < 2097152) {
    const float* src;
    unsigned short* dst;
    int off;
    if (i < 1048576) { src = x; dst = xb; off = i; }
    else if (i < 1835008) { src = wqkv; dst = wqkvb; off = i - 1048576; }
    else { src = wproj; dst = wprojb; off = i - 1835008; }
    f32x4 v = *(const f32x4*)(src + (size_t)off * 4);
    u16x4 o;
#pragma unroll
    for (int j = 0; j < 4; ++j) o[j] = f2bf(v[j]);
    *(u16x4*)(dst + (size_t)off * 4) = o;
  } else {
    int gid = i - 2097152;        // 0..262143
    int q = gid & 2047;
    int plane = gid >> 11;        // 0..127
    int h = plane & 1;
    int kn = plane >> 1;          // kt*4+n : 0..63
    const float* src = ab + (size_t)q * 2048 + kn * 32 + h * 4;
    unsigned short* dst = B2 + (size_t)plane * 32768 + q * 16;
#pragma unroll
    for (int Qd = 0; Qd < 4; ++Qd) {
      f32x4 v = *(const f32x4*)(src + Qd * 8);  // k = kn*32+4h+8Qd+{0..3}
      u16x4 o;
#pragma unroll
      for (int r = 0; r < 4; ++r) o[r] = f2bf(v[r] * 1.44269504088896f);
      *(u16x4*)(dst + Qd * 4) = o;
    }
  }
}

// ---------------- QKV GEMM: 8-phase 256x256 + T2 LDS XOR-swizzle (r18) ----------------
__global__ __launch_bounds__(512) void gemm_qkv(
    const unsigned short* __restrict__ A, const unsigned short* __restrict__ Bm,
    unsigned short* __restrict__ qn, unsigned short* __restrict__ kn,
    unsigned short* __restrict__ vt,
    const float* __restrict__ bias_q, const float* __restrict__ bias_v,
    const float* __restrict__ scale_mul) {
  __shared__ unsigned short Al[2][16384];  // [slot][256 rows x 64 k] (32KB/slot)
  __shared__ unsigned short Bl[2][16384];
  const int tid = threadIdx.x;   // 0..511
  const int lane = tid & 63;
  const int wave = tid >> 6;     // 0..7
  const int wr = wave >> 2;      // 0..1  (row half: 128 rows)
  const int wcn = wave & 3;      // 0..3  (col quarter: 64 cols)
  const int c = lane & 15, g = lane >> 4;
  const int rowBase = blockIdx.x * 256;
  const int colBase = blockIdx.y * 256;
  const int srow = tid >> 3;                          // 0..63 within round
  const int scol = (((tid & 7) ^ (srow & 7)) * 8);    // u16 col, PRE-SWIZZLED (T21)

  auto STAGE_A = [&](int kt, int half) {
    int slot = kt & 1;
#pragma unroll
    for (int rr = 0; rr < 2; ++rr) {
      int r = half * 2 + rr;
      gl_lds16(A + (size_t)(rowBase + r * 64 + srow) * 1024 + kt * 64 + scol,
               &Al[slot][r * 4096 + wave * 512]);
    }
  };
  auto STAGE_B = [&](int kt, int half) {
    int slot = kt & 1;
#pragma unroll
    for (int rr = 0; rr < 2; ++rr) {
      int r = half * 2 + rr;
      gl_lds16(Bm + (size_t)(colBase + r * 64 + srow) * 1024 + kt * 64 + scol,
               &Bl[slot][r * 4096 + wave * 512]);
    }
  };
  auto LDA = [&](int slot, int row, int colu) -> short8v {
    return *(const short8v*)&Al[slot][row * 64 + (colu ^ ((row & 7) << 3))];
  };
  auto LDB = [&](int slot, int row, int colu) -> short8v {
    return *(const short8v*)&Bl[slot][row * 64 + (colu ^ ((row & 7) << 3))];
  };

  f32x4 acc[8][4];
#pragma unroll
  for (int m = 0; m < 8; ++m)
#pragma unroll
    for (int n = 0; n < 4; ++n) acc[m][n] = (f32x4){0.f, 0.f, 0.f, 0.f};

  short8v af[4][2];
  short8v bf[2][2];

  // prologue: stage whole tile 0 in ledger order A0,B0,B1,A1
  STAGE_A(0, 0);
  STAGE_B(0, 0);
  STAGE_B(0, 1);
  STAGE_A(0, 1);

  for (int kt = 0; kt < 16; ++kt) {
    const int slot = kt & 1;
    const bool more = (kt + 1) < 16;

    // ---- P0: quadrant (0,0) ----
    __builtin_amdgcn_s_barrier();  // b1: all waves done reading slot^1 (kt-1)
    if (more) STAGE_A(kt + 1, 0);
    if (more) asm volatile("s_waitcnt vmcnt(4)" ::: "memory");
    else      asm volatile("s_waitcnt vmcnt(2)" ::: "memory");
    __builtin_amdgcn_s_barrier();  // b2: A0,B0,B1(kt) visible block-wide
#pragma unroll
    for (int mm = 0; mm < 4; ++mm)
#pragma unroll
      for (int kk = 0; kk < 2; ++kk)
        af[mm][kk] = LDA(slot, wr * 128 + mm * 16 + c, kk * 32 + g * 8);
#pragma unroll
    for (int nn = 0; nn < 2; ++nn)
#pragma unroll
      for (int kk = 0; kk < 2; ++kk)
        bf[nn][kk] = LDB(slot, wcn * 64 + nn * 16 + c, kk * 32 + g * 8);
    __builtin_amdgcn_s_setprio(1);
#pragma unroll
    for (int mm = 0; mm < 4; ++mm)
#pragma unroll
      for (int nn = 0; nn < 2; ++nn)
#pragma unroll
        for (int kk = 0; kk < 2; ++kk)
          acc[mm][nn] = MFMA16(af[mm][kk], bf[nn][kk], acc[mm][nn]);
    __builtin_amdgcn_s_setprio(0);

    // ---- P1: quadrant (0,1) ----
    if (more) STAGE_B(kt + 1, 0);
#pragma unroll
    for (int nn = 0; nn < 2; ++nn)
#pragma unroll
      for (int kk = 0; kk < 2; ++kk)
        bf[nn][kk] = LDB(slot, wcn * 64 + (2 + nn) * 16 + c, kk * 32 + g * 8);
    __builtin_amdgcn_s_setprio(1);
#pragma unroll
    for (int mm = 0; mm < 4; ++mm)
#pragma unroll
      for (int nn = 0; nn < 2; ++nn)
#pragma unroll
        for (int kk = 0; kk < 2; ++kk)
          acc[mm][2 + nn] = MFMA16(af[mm][kk], bf[nn][kk], acc[mm][2 + nn]);
    __builtin_amdgcn_s_setprio(0);

    // ---- P2: quadrant (1,1) ----
    if (more) STAGE_B(kt + 1, 1);
    if (more) asm volatile("s_waitcnt vmcnt(6)" ::: "memory");
    else      asm volatile("s_waitcnt vmcnt(0)" ::: "memory");
    __builtin_amdgcn_s_barrier();  // b3: A1(kt) visible block-wide
#pragma unroll
    for (int mm = 0; mm < 4; ++mm)
#pragma unroll
      for (int kk = 0; kk < 2; ++kk)
        af[mm][kk] = LDA(slot, wr * 128 + (4 + mm) * 16 + c, kk * 32 + g * 8);
    __builtin_amdgcn_s_setprio(1);
#pragma unroll
    for (int mm = 0; mm < 4; ++mm)
#pragma unroll
      for (int nn = 0; nn < 2; ++nn)
#pragma unroll
        for (int kk = 0; kk < 2; ++kk)
          acc[4 + mm][2 + nn] = MFMA16(af[mm][kk], bf[nn][kk], acc[4 + mm][2 + nn]);
    __builtin_amdgcn_s_setprio(0);

    // ---- P3: quadrant (1,0) ----
    if (more) STAGE_A(kt + 1, 1);
#pragma unroll
    for (int nn = 0; nn < 2; ++nn)
#pragma unroll
      for (int kk = 0; kk < 2; ++kk)
        bf[nn][kk] = LDB(slot, wcn * 64 + nn * 16 + c, kk * 32 + g * 8);
    __builtin_amdgcn_s_setprio(1);
#pragma unroll
    for (int mm = 0; mm < 4; ++mm)
#pragma unroll
      for (int nn = 0; nn < 2; ++nn)
#pragma unroll
        for (int kk = 0; kk < 2; ++kk)
          acc[4 + mm][nn] = MFMA16(af[mm][kk], bf[nn][kk], acc[4 + mm][nn]);
    __builtin_amdgcn_s_setprio(0);
  }

  // ---------------- epilogue ----------------
  const int sec = colBase >> 10;                   // 0=q 1=k 2=v (block-uniform)
  const int jbase = (colBase & 1023) + wcn * 64;   // head-col base (wave-uniform)
  const int headCol = jbase >> 6;
  const int bI = rowBase >> 11;
  const int bhh = bI * 16 + headCol;

  if (sec == 2) {
    // V: bias add, per-wave swizzled LDS transpose (two 64x64 sub-tiles),
    // coalesced vt [B,H,D,L] writes. Scratch aliases Al (all compute done).
    __syncthreads();
    unsigned short* tls = &Al[0][0] + wave * 4096;  // per-wave 64x64 u16
#pragma unroll
    for (int lh = 0; lh < 2; ++lh) {
      const int lbase = (rowBase & 2047) + wr * 128 + lh * 64;
#pragma unroll
      for (int mq = 0; mq < 4; ++mq)
#pragma unroll
        for (int r = 0; r < 4; ++r)
#pragma unroll
          for (int n = 0; n < 4; ++n) {
            int d = n * 16 + c;
            int ll = mq * 16 + g * 4 + r;
            tls[d * 64 + (ll ^ ((d & 7) << 3))] =
                f2bf(acc[lh * 4 + mq][n][r] + bias_v[jbase + n * 16 + c]);
          }
      // per-wave-private region: compiler lgkm ordering suffices (no barrier)
#pragma unroll
      for (int j = 0; j < 8; ++j) {
        int idx = j * 64 + lane;
        int d = idx >> 3;
        int l8 = (idx & 7) * 8;
        short8v v8 = *(const short8v*)&tls[d * 64 + (l8 ^ ((d & 7) << 3))];
        *(short8v*)(vt + ((size_t)(bhh * 64 + d)) * 2048 + lbase + l8) = v8;
      }
    }
  } else {
    float qsc = 1.0f;
    if (sec == 0)
      qsc = __expf(fminf(scale_mul[headCol], 4.605170185988091f)) * 1.44269504088896f;
#pragma unroll
    for (int m = 0; m < 8; ++m) {
#pragma unroll
      for (int r = 0; r < 4; ++r) {
        float vv[4];
#pragma unroll
        for (int n = 0; n < 4; ++n) {
          int jn = jbase + n * 16 + c;
          float bias = (sec == 0) ? bias_q[jn] : 0.0f;
          vv[n] = acc[m][n][r] + bias;
        }
        // l2-norm across the 64 d-values of this row-head (4 regs x 16 c-lanes)
        float ss = vv[0] * vv[0] + vv[1] * vv[1] + vv[2] * vv[2] + vv[3] * vv[3];
        ss += __shfl_xor(ss, 1);
        ss += __shfl_xor(ss, 2);
        ss += __shfl_xor(ss, 4);
        ss += __shfl_xor(ss, 8);
        float sc = qsc / fmaxf(sqrtf(ss), 1e-12f);
        int grow = rowBase + wr * 128 + m * 16 + g * 4 + r;
        int l = grow & 2047;
#pragma unroll
        for (int n = 0; n < 4; ++n) {
          int d = n * 16 + c;
          unsigned short o = f2bf(vv[n] * sc);
          if (sec == 0)
            qn[(bhh * 2048 + l) * 64 + d] = o;
          else
            kn[(bhh * 2048 + l) * 64 + d] = o;
        }
      }
    }
  }
}

// ---------------- proj GEMM: out = oup @ w_proj^T + b_proj (fp32 out) ----------
__global__ __launch_bounds__(256) void gemm_proj(
    const unsigned short* __restrict__ A, const unsigned short* __restrict__ Bm,
    float* __restrict__ outf, const float* __restrict__ bias) {
  __shared__ unsigned short Asl[64 * 64];   // 8KB
  __shared__ unsigned short Bsl[64 * 64];   // 8KB
  const int tid = threadIdx.x;
  const int lane = tid & 63;
  const int wave = tid >> 6;
  const int wr = wave >> 1, wc = wave & 1;
  const int c = lane & 15, g = lane >> 4;
  const int rowBase = blockIdx.x * 64;
  const int colBase = blockIdx.y * 64;
  const int srow = lane >> 3, scol = (lane & 7) * 8;

  f32x4 acc[2][2];
#pragma unroll
  for (int m = 0; m < 2; ++m)
#pragma unroll
    for (int n = 0; n < 2; ++n) acc[m][n] = (f32x4){0.f, 0.f, 0.f, 0.f};

  for (int k0 = 0; k0 < 1024; k0 += 64) {
#pragma unroll
    for (int it = 0; it < 2; ++it) {
      int ci = wave * 2 + it;
      int r = ci * 8 + srow;
      gl_lds16(A + (size_t)(rowBase + r) * 1024 + k0 + scol, &Asl[ci * 512]);
      gl_lds16(Bm + (size_t)(colBase + r) * 1024 + k0 + scol, &Bsl[ci * 512]);
    }
    __syncthreads();
#pragma unroll
    for (int kk = 0; kk < 2; ++kk) {
      short8v af[2], bfr[2];
#pragma unroll
      for (int m = 0; m < 2; ++m)
        af[m] = *(const short8v*)&Asl[(wr * 32 + m * 16 + c) * 64 + kk * 32 + g * 8];
#pragma unroll
      for (int n = 0; n < 2; ++n)
        bfr[n] = *(const short8v*)&Bsl[(wc * 32 + n * 16 + c) * 64 + kk * 32 + g * 8];
#pragma unroll
      for (int m = 0; m < 2; ++m)
#pragma unroll
        for (int n = 0; n < 2; ++n) acc[m][n] = MFMA16(af[m], bfr[n], acc[m][n]);
    }
    __syncthreads();
  }

#pragma unroll
  for (int m = 0; m < 2; ++m)
#pragma unroll
    for (int n = 0; n < 2; ++n)
#pragma unroll
      for (int r = 0; r < 4; ++r) {
        int grow = rowBase + wr * 32 + m * 16 + g * 4 + r;
        int gcol = colBase + wc * 32 + n * 16 + c;
        outf[(size_t)grow * 1024 + gcol] = acc[m][n][r] + bias[gcol];
      }
}

// ---------------- flash attention: KV128 + packed bias + permlane exchange ----------
// No-max softmax (scores bounded: |S*log2e| <= 5.9 by l2-norm construction).
// 4 waves x 32 q-rows = 128 q/block; KV tile 128 (4 sequential 32-k subtiles).
// Bias from B2[plane][q][e] (r19). NEW (T12 primitive): A-frag build uses
// v_permlane32_swap_b32 instead of select+shfl_xor(32)+select — one swap per u
// yields both needed words (A' = own/partner first-half, B' = second-half),
// replacing ~10 VALU/ds_bpermute ops per kc with 2 permlane instructions.
// NOTE: no min-waves launch bound ((256,4) caused 300MB scratch spills, r6-7).
__global__ __launch_bounds__(256) void attn_fwd(
    const unsigned short* __restrict__ qn, const unsigned short* __restrict__ kn,
    const unsigned short* __restrict__ vt, const unsigned short* __restrict__ biasb,
    unsigned short* __restrict__ oup) {
  __shared__ unsigned short Ksl[2][128][72];
  __shared__ unsigned short Vsl[2][64][136];
  const int tid = threadIdx.x;
  const int lane = tid & 63;
  const int wave = tid >> 6;
  const int c5 = lane & 31;
  const int h = lane >> 5;
  const int qt = blockIdx.x;   // 16
  const int bh = blockIdx.y;   // 32
  const int b = bh >> 4, hd = bh & 15;
  const int q = qt * 128 + wave * 32 + c5;

  short8v qf[4];
  {
    const unsigned short* qp = qn + ((size_t)bh * 2048 + q) * 64 + h * 8;
#pragma unroll
    for (int kd = 0; kd < 4; ++kd) qf[kd] = *(const short8v*)(qp + kd * 16);
  }
  const unsigned short* kb = kn + (size_t)bh * 131072;
  const unsigned short* vb = vt + (size_t)bh * 131072;
  // fragment-packed bias base for this lane: B2[plane][q][e], plane=(kt*4+n)*2+h
  const unsigned short* bq = biasb + (size_t)q * 16 + (size_t)h * 32768;

  int rk[4], ck[4], rv[4], cv[4];
#pragma unroll
  for (int i = 0; i < 4; ++i) {
    int flat = tid * 8 + i * 2048;
    rk[i] = flat >> 6;  ck[i] = flat & 63;
    rv[i] = flat >> 7;  cv[i] = flat & 127;
  }

  int4v kreg[4], vreg[4];
  u16x4 bb[4][4];

  auto ISSUE = [&](int kt) {
#pragma unroll
    for (int i = 0; i < 4; ++i) {
      kreg[i] = *(const int4v*)(kb + (size_t)(kt * 128 + rk[i]) * 64 + ck[i]);
      vreg[i] = *(const int4v*)(vb + (size_t)rv[i] * 2048 + kt * 128 + cv[i]);
    }
  };
  auto ISSUEB = [&](int n, int kt) {
    const unsigned short* p = bq + (size_t)(kt * 4 + n) * 65536;  // *2 planes*32768
#pragma unroll
    for (int Qd = 0; Qd < 4; ++Qd)
      bb[n][Qd] = *(const u16x4*)(p + Qd * 4);
  };
  auto WRITE = [&](int buf) {
#pragma unroll
    for (int i = 0; i < 4; ++i) {
      *(int4v*)&Ksl[buf][rk[i]][ck[i]] = kreg[i];
      *(int4v*)&Vsl[buf][rv[i]][cv[i]] = vreg[i];
    }
  };

  float l_run = 0.0f;
  f32x16 o0 = {}, o1 = {};

  ISSUE(0);
#pragma unroll
  for (int n = 0; n < 4; ++n) ISSUEB(n, 0);
  WRITE(0);
  __syncthreads();

  for (int kt = 0; kt < 16; ++kt) {
    const int cur = kt & 1;
    const bool more = (kt + 1) < 16;
    if (more) ISSUE(kt + 1);
    float rs = 0.0f;

#pragma unroll
    for (int n = 0; n < 4; ++n) {
      f32x16 s;
#pragma unroll
      for (int Qd = 0; Qd < 4; ++Qd)
#pragma unroll
        for (int r = 0; r < 4; ++r) s[Qd * 4 + r] = bf2f(bb[n][Qd][r]);
      if (more) ISSUEB(n, kt + 1);

      __builtin_amdgcn_s_setprio(1);
#pragma unroll
      for (int kd = 0; kd < 4; ++kd) {
        short8v kf = *(const short8v*)&Ksl[cur][n * 32 + c5][kd * 16 + h * 8];
        s = MFMA32(kf, qf[kd], s);
      }
      __builtin_amdgcn_s_setprio(0);

#pragma unroll
      for (int e = 0; e < 16; ++e) {
        float p = exp2_hw(s[e]);
        s[e] = p;
        rs += p;
      }

      unsigned int w[4][2];
#pragma unroll
      for (int Qd = 0; Qd < 4; ++Qd) {
        asm("v_cvt_pk_bf16_f32 %0, %1, %2"
            : "=v"(w[Qd][0]) : "v"(s[Qd * 4 + 0]), "v"(s[Qd * 4 + 1]));
        asm("v_cvt_pk_bf16_f32 %0, %1, %2"
            : "=v"(w[Qd][1]) : "v"(s[Qd * 4 + 2]), "v"(s[Qd * 4 + 3]));
      }

      // A-frags via v_permlane32_swap (dst.hi <-> src.lo):
      // swap(A,B): A'[32+i]=B[i], B'[i]=A[32+i], A'.lo/B'.hi unchanged.
      // Per-lane read: A' = {h=0: A own | h=1: B partner} = W[u];
      //                B' = {h=0: A partner??} -- verified: W[u]=A', W[2+u]=B'
      // reproduces exactly (pub=h?A:B; ex=shfl_xor(pub,32); W[u]=h?ex:A;
      // W[2+u]=h?B:ex) for this A/B pairing.
      __builtin_amdgcn_s_setprio(1);
#pragma unroll
      for (int kc = 0; kc < 2; ++kc) {
        unsigned int a0 = w[kc * 2][0], a1 = w[kc * 2][1];
        unsigned int b0 = w[kc * 2 + 1][0], b1 = w[kc * 2 + 1][1];
        asm volatile("v_permlane32_swap_b32 %0, %1" : "+v"(a0), "+v"(b0));
        asm volatile("v_permlane32_swap_b32 %0, %1" : "+v"(a1), "+v"(b1));
        uint4v wv = {a0, a1, b0, b1};
        short8v pa = __builtin_bit_cast(short8v, wv);
        short8v v0 = *(const short8v*)&Vsl[cur][c5][n * 32 + kc * 16 + h * 8];
        short8v v1 = *(const short8v*)&Vsl[cur][32 + c5][n * 32 + kc * 16 + h * 8];
        o0 = MFMA32(pa, v0, o0);
        o1 = MFMA32(pa, v1, o1);
      }
      __builtin_amdgcn_s_setprio(0);
    }

    rs += __shfl_xor(rs, 32);
    l_run += rs;

    if (more) WRITE(cur ^ 1);
    __syncthreads();
  }

  float linv = 1.0f / l_run;
#pragma unroll
  for (int e = 0; e < 16; ++e) {
    int ql = (e & 3) + 8 * (e >> 2) + 4 * h;
    float inv = __shfl(linv, ql);
    int grow = b * 2048 + qt * 128 + wave * 32 + ql;
    oup[(size_t)grow * 1024 + hd * 64 + c5] = f2bf(o0[e] * inv);
    oup[(size_t)grow * 1024 + hd * 64 + 32 + c5] = f2bf(o1[e] * inv);
  }
}

// ---------------- host launch ----------------
extern "C" void kernel_launch(void* const* d_in, const int* in_sizes, int n_in,
                              void* d_out, int out_size, void* d_ws, size_t ws_size,
                              hipStream_t stream) {
  const float* x = (const float*)d_in[0];
  const float* attn_bias = (const float*)d_in[1];
  const float* w_qkv = (const float*)d_in[2];
  const float* q_bias = (const float*)d_in[3];
  const float* v_bias = (const float*)d_in[4];
  const float* scale_mul = (const float*)d_in[5];
  const float* w_proj = (const float*)d_in[6];
  const float* b_proj = (const float*)d_in[7];
  float* out = (float*)d_out;

  char* ws = (char*)d_ws;
  unsigned short* xb = (unsigned short*)(ws);                   // [4096][1024] bf16
  unsigned short* oup = (unsigned short*)(ws);                  // alias (disjoint lifetime)
  unsigned short* wqkvb = (unsigned short*)(ws + (8 << 20));    // [3072][1024]
  unsigned short* wprojb = (unsigned short*)(ws + (14 << 20));  // [1024][1024]
  unsigned short* biasb = (unsigned short*)(ws + (16 << 20));   // B2 [128][2048][16] (*log2e)
  unsigned short* qn = (unsigned short*)(ws + (24 << 20));      // [32][2048][64]
  unsigned short* kn = (unsigned short*)(ws + (32 << 20));      // [32][2048][64]
  unsigned short* vt = (unsigned short*)(ws + (40 << 20));      // [32][64][2048]

  prep_all<<<9216, 256, 0, stream>>>(x, w_qkv, w_proj, attn_bias, xb, wqkvb,
                                     wprojb, biasb);
  gemm_qkv<<<dim3(16, 12), 512, 0, stream>>>(xb, wqkvb, qn, kn, vt, q_bias,
                                             v_bias, scale_mul);
  attn_fwd<<<dim3(16, 32), 256, 0, stream>>>(qn, kn, vt, biasb, oup);
  gemm_proj<<<dim3(64, 16), 256, 0, stream>>>(oup, wprojb, out, b_proj);
}

// Round 22
// 144.784 us; speedup vs baseline: 1.1544x; 1.0072x over previous
//
#include <hip/hip_runtime.h>

typedef __attribute__((ext_vector_type(8))) short short8v;
typedef __attribute__((ext_vector_type(4))) float f32x4;
typedef __attribute__((ext_vector_type(16))) float f32x16;
typedef __attribute__((ext_vector_type(4))) int int4v;
typedef __attribute__((ext_vector_type(4))) unsigned int uint4v;
typedef __attribute__((ext_vector_type(4))) unsigned short u16x4;

#define MFMA16(a, b, c) __builtin_amdgcn_mfma_f32_16x16x32_bf16(a, b, c, 0, 0, 0)
#define MFMA32(a, b, c) __builtin_amdgcn_mfma_f32_32x32x16_bf16(a, b, c, 0, 0, 0)

__device__ __forceinline__ unsigned short f2bf(float f) {
  unsigned int u = __builtin_bit_cast(unsigned int, f);
  return (unsigned short)((u + 0x7FFFu + ((u >> 16) & 1u)) >> 16);
}
__device__ __forceinline__ float bf2f(unsigned short s) {
  return __builtin_bit_cast(float, (unsigned int)s << 16);
}
__device__ __forceinline__ float exp2_hw(float x) {
  float r;
  asm("v_exp_f32 %0, %1" : "=v"(r) : "v"(x));
  return r;
}
// async global->LDS, 16B/lane; lds base wave-uniform (HW adds lane*16)
__device__ __forceinline__ void gl_lds16(const unsigned short* g, unsigned short* l) {
  __builtin_amdgcn_global_load_lds(
      (const __attribute__((address_space(1))) void*)g,
      (__attribute__((address_space(3))) void*)l, 16, 0, 0);
}

// ---------------- fused prep: fp32->bf16 casts + fragment-ordered bias pack ----
__global__ __launch_bounds__(256) void prep_all(
    const float* __restrict__ x, const float* __restrict__ wqkv,
    const float* __restrict__ wproj, const float* __restrict__ ab,
    unsigned short* __restrict__ xb, unsigned short* __restrict__ wqkvb,
    unsigned short* __restrict__ wprojb, unsigned short* __restrict__ B2) {
  int i = blockIdx.x * 256 + threadIdx.x;  // 0 .. 2359295
  if (i < 2097152) {
    const float* src;
    unsigned short* dst;
    int off;
    if (i < 1048576) { src = x; dst = xb; off = i; }
    else if (i < 1835008) { src = wqkv; dst = wqkvb; off = i - 1048576; }
    else { src = wproj; dst = wprojb; off = i - 1835008; }
    f32x4 v = *(const f32x4*)(src + (size_t)off * 4);
    u16x4 o;
#pragma unroll
    for (int j = 0; j < 4; ++j) o[j] = f2bf(v[j]);
    *(u16x4*)(dst + (size_t)off * 4) = o;
  } else {
    int gid = i - 2097152;        // 0..262143
    int q = gid & 2047;
    int plane = gid >> 11;        // 0..127
    int h = plane & 1;
    int kn = plane >> 1;          // kt*4+n : 0..63
    const float* src = ab + (size_t)q * 2048 + kn * 32 + h * 4;
    unsigned short* dst = B2 + (size_t)plane * 32768 + q * 16;
#pragma unroll
    for (int Qd = 0; Qd < 4; ++Qd) {
      f32x4 v = *(const f32x4*)(src + Qd * 8);  // k = kn*32+4h+8Qd+{0..3}
      u16x4 o;
#pragma unroll
      for (int r = 0; r < 4; ++r) o[r] = f2bf(v[r] * 1.44269504088896f);
      *(u16x4*)(dst + Qd * 4) = o;
    }
  }
}

// ---------------- QKV GEMM: 8-phase 256x256 + T2 LDS XOR-swizzle (r18) ----------------
__global__ __launch_bounds__(512) void gemm_qkv(
    const unsigned short* __restrict__ A, const unsigned short* __restrict__ Bm,
    unsigned short* __restrict__ qn, unsigned short* __restrict__ kn,
    unsigned short* __restrict__ vt,
    const float* __restrict__ bias_q, const float* __restrict__ bias_v,
    const float* __restrict__ scale_mul) {
  __shared__ unsigned short Al[2][16384];  // [slot][256 rows x 64 k] (32KB/slot)
  __shared__ unsigned short Bl[2][16384];
  const int tid = threadIdx.x;   // 0..511
  const int lane = tid & 63;
  const int wave = tid >> 6;     // 0..7
  const int wr = wave >> 2;      // 0..1  (row half: 128 rows)
  const int wcn = wave & 3;      // 0..3  (col quarter: 64 cols)
  const int c = lane & 15, g = lane >> 4;
  const int rowBase = blockIdx.x * 256;
  const int colBase = blockIdx.y * 256;
  const int srow = tid >> 3;                          // 0..63 within round
  const int scol = (((tid & 7) ^ (srow & 7)) * 8);    // u16 col, PRE-SWIZZLED (T21)

  auto STAGE_A = [&](int kt, int half) {
    int slot = kt & 1;
#pragma unroll
    for (int rr = 0; rr < 2; ++rr) {
      int r = half * 2 + rr;
      gl_lds16(A + (size_t)(rowBase + r * 64 + srow) * 1024 + kt * 64 + scol,
               &Al[slot][r * 4096 + wave * 512]);
    }
  };
  auto STAGE_B = [&](int kt, int half) {
    int slot = kt & 1;
#pragma unroll
    for (int rr = 0; rr < 2; ++rr) {
      int r = half * 2 + rr;
      gl_lds16(Bm + (size_t)(colBase + r * 64 + srow) * 1024 + kt * 64 + scol,
               &Bl[slot][r * 4096 + wave * 512]);
    }
  };
  auto LDA = [&](int slot, int row, int colu) -> short8v {
    return *(const short8v*)&Al[slot][row * 64 + (colu ^ ((row & 7) << 3))];
  };
  auto LDB = [&](int slot, int row, int colu) -> short8v {
    return *(const short8v*)&Bl[slot][row * 64 + (colu ^ ((row & 7) << 3))];
  };

  f32x4 acc[8][4];
#pragma unroll
  for (int m = 0; m < 8; ++m)
#pragma unroll
    for (int n = 0; n < 4; ++n) acc[m][n] = (f32x4){0.f, 0.f, 0.f, 0.f};

  short8v af[4][2];
  short8v bf[2][2];

  // prologue: stage whole tile 0 in ledger order A0,B0,B1,A1
  STAGE_A(0, 0);
  STAGE_B(0, 0);
  STAGE_B(0, 1);
  STAGE_A(0, 1);

  for (int kt = 0; kt < 16; ++kt) {
    const int slot = kt & 1;
    const bool more = (kt + 1) < 16;

    // ---- P0: quadrant (0,0) ----
    __builtin_amdgcn_s_barrier();  // b1: all waves done reading slot^1 (kt-1)
    if (more) STAGE_A(kt + 1, 0);
    if (more) asm volatile("s_waitcnt vmcnt(4)" ::: "memory");
    else      asm volatile("s_waitcnt vmcnt(2)" ::: "memory");
    __builtin_amdgcn_s_barrier();  // b2: A0,B0,B1(kt) visible block-wide
#pragma unroll
    for (int mm = 0; mm < 4; ++mm)
#pragma unroll
      for (int kk = 0; kk < 2; ++kk)
        af[mm][kk] = LDA(slot, wr * 128 + mm * 16 + c, kk * 32 + g * 8);
#pragma unroll
    for (int nn = 0; nn < 2; ++nn)
#pragma unroll
      for (int kk = 0; kk < 2; ++kk)
        bf[nn][kk] = LDB(slot, wcn * 64 + nn * 16 + c, kk * 32 + g * 8);
    __builtin_amdgcn_s_setprio(1);
#pragma unroll
    for (int mm = 0; mm < 4; ++mm)
#pragma unroll
      for (int nn = 0; nn < 2; ++nn)
#pragma unroll
        for (int kk = 0; kk < 2; ++kk)
          acc[mm][nn] = MFMA16(af[mm][kk], bf[nn][kk], acc[mm][nn]);
    __builtin_amdgcn_s_setprio(0);

    // ---- P1: quadrant (0,1) ----
    if (more) STAGE_B(kt + 1, 0);
#pragma unroll
    for (int nn = 0; nn < 2; ++nn)
#pragma unroll
      for (int kk = 0; kk < 2; ++kk)
        bf[nn][kk] = LDB(slot, wcn * 64 + (2 + nn) * 16 + c, kk * 32 + g * 8);
    __builtin_amdgcn_s_setprio(1);
#pragma unroll
    for (int mm = 0; mm < 4; ++mm)
#pragma unroll
      for (int nn = 0; nn < 2; ++nn)
#pragma unroll
        for (int kk = 0; kk < 2; ++kk)
          acc[mm][2 + nn] = MFMA16(af[mm][kk], bf[nn][kk], acc[mm][2 + nn]);
    __builtin_amdgcn_s_setprio(0);

    // ---- P2: quadrant (1,1) ----
    if (more) STAGE_B(kt + 1, 1);
    if (more) asm volatile("s_waitcnt vmcnt(6)" ::: "memory");
    else      asm volatile("s_waitcnt vmcnt(0)" ::: "memory");
    __builtin_amdgcn_s_barrier();  // b3: A1(kt) visible block-wide
#pragma unroll
    for (int mm = 0; mm < 4; ++mm)
#pragma unroll
      for (int kk = 0; kk < 2; ++kk)
        af[mm][kk] = LDA(slot, wr * 128 + (4 + mm) * 16 + c, kk * 32 + g * 8);
    __builtin_amdgcn_s_setprio(1);
#pragma unroll
    for (int mm = 0; mm < 4; ++mm)
#pragma unroll
      for (int nn = 0; nn < 2; ++nn)
#pragma unroll
        for (int kk = 0; kk < 2; ++kk)
          acc[4 + mm][2 + nn] = MFMA16(af[mm][kk], bf[nn][kk], acc[4 + mm][2 + nn]);
    __builtin_amdgcn_s_setprio(0);

    // ---- P3: quadrant (1,0) ----
    if (more) STAGE_A(kt + 1, 1);
#pragma unroll
    for (int nn = 0; nn < 2; ++nn)
#pragma unroll
      for (int kk = 0; kk < 2; ++kk)
        bf[nn][kk] = LDB(slot, wcn * 64 + nn * 16 + c, kk * 32 + g * 8);
    __builtin_amdgcn_s_setprio(1);
#pragma unroll
    for (int mm = 0; mm < 4; ++mm)
#pragma unroll
      for (int nn = 0; nn < 2; ++nn)
#pragma unroll
        for (int kk = 0; kk < 2; ++kk)
          acc[4 + mm][nn] = MFMA16(af[mm][kk], bf[nn][kk], acc[4 + mm][nn]);
    __builtin_amdgcn_s_setprio(0);
  }

  // ---------------- epilogue ----------------
  const int sec = colBase >> 10;                   // 0=q 1=k 2=v (block-uniform)
  const int jbase = (colBase & 1023) + wcn * 64;   // head-col base (wave-uniform)
  const int headCol = jbase >> 6;
  const int bI = rowBase >> 11;
  const int bhh = bI * 16 + headCol;

  if (sec == 2) {
    // V: bias add, per-wave swizzled LDS transpose (two 64x64 sub-tiles),
    // coalesced vt [B,H,D,L] writes. Scratch aliases Al (all compute done).
    __syncthreads();
    unsigned short* tls = &Al[0][0] + wave * 4096;  // per-wave 64x64 u16
#pragma unroll
    for (int lh = 0; lh < 2; ++lh) {
      const int lbase = (rowBase & 2047) + wr * 128 + lh * 64;
#pragma unroll
      for (int mq = 0; mq < 4; ++mq)
#pragma unroll
        for (int r = 0; r < 4; ++r)
#pragma unroll
          for (int n = 0; n < 4; ++n) {
            int d = n * 16 + c;
            int ll = mq * 16 + g * 4 + r;
            tls[d * 64 + (ll ^ ((d & 7) << 3))] =
                f2bf(acc[lh * 4 + mq][n][r] + bias_v[jbase + n * 16 + c]);
          }
      // per-wave-private region: compiler lgkm ordering suffices (no barrier)
#pragma unroll
      for (int j = 0; j < 8; ++j) {
        int idx = j * 64 + lane;
        int d = idx >> 3;
        int l8 = (idx & 7) * 8;
        short8v v8 = *(const short8v*)&tls[d * 64 + (l8 ^ ((d & 7) << 3))];
        *(short8v*)(vt + ((size_t)(bhh * 64 + d)) * 2048 + lbase + l8) = v8;
      }
    }
  } else {
    float qsc = 1.0f;
    if (sec == 0)
      qsc = __expf(fminf(scale_mul[headCol], 4.605170185988091f)) * 1.44269504088896f;
#pragma unroll
    for (int m = 0; m < 8; ++m) {
#pragma unroll
      for (int r = 0; r < 4; ++r) {
        float vv[4];
#pragma unroll
        for (int n = 0; n < 4; ++n) {
          int jn = jbase + n * 16 + c;
          float bias = (sec == 0) ? bias_q[jn] : 0.0f;
          vv[n] = acc[m][n][r] + bias;
        }
        // l2-norm across the 64 d-values of this row-head (4 regs x 16 c-lanes)
        float ss = vv[0] * vv[0] + vv[1] * vv[1] + vv[2] * vv[2] + vv[3] * vv[3];
        ss += __shfl_xor(ss, 1);
        ss += __shfl_xor(ss, 2);
        ss += __shfl_xor(ss, 4);
        ss += __shfl_xor(ss, 8);
        float sc = qsc / fmaxf(sqrtf(ss), 1e-12f);
        int grow = rowBase + wr * 128 + m * 16 + g * 4 + r;
        int l = grow & 2047;
#pragma unroll
        for (int n = 0; n < 4; ++n) {
          int d = n * 16 + c;
          unsigned short o = f2bf(vv[n] * sc);
          if (sec == 0)
            qn[(bhh * 2048 + l) * 64 + d] = o;
          else
            kn[(bhh * 2048 + l) * 64 + d] = o;
        }
      }
    }
  }
}

// ---------------- proj GEMM: out = oup @ w_proj^T + b_proj (fp32 out) ----------
__global__ __launch_bounds__(256) void gemm_proj(
    const unsigned short* __restrict__ A, const unsigned short* __restrict__ Bm,
    float* __restrict__ outf, const float* __restrict__ bias) {
  __shared__ unsigned short Asl[64 * 64];   // 8KB
  __shared__ unsigned short Bsl[64 * 64];   // 8KB
  const int tid = threadIdx.x;
  const int lane = tid & 63;
  const int wave = tid >> 6;
  const int wr = wave >> 1, wc = wave & 1;
  const int c = lane & 15, g = lane >> 4;
  const int rowBase = blockIdx.x * 64;
  const int colBase = blockIdx.y * 64;
  const int srow = lane >> 3, scol = (lane & 7) * 8;

  f32x4 acc[2][2];
#pragma unroll
  for (int m = 0; m < 2; ++m)
#pragma unroll
    for (int n = 0; n < 2; ++n) acc[m][n] = (f32x4){0.f, 0.f, 0.f, 0.f};

  for (int k0 = 0; k0 < 1024; k0 += 64) {
#pragma unroll
    for (int it = 0; it < 2; ++it) {
      int ci = wave * 2 + it;
      int r = ci * 8 + srow;
      gl_lds16(A + (size_t)(rowBase + r) * 1024 + k0 + scol, &Asl[ci * 512]);
      gl_lds16(Bm + (size_t)(colBase + r) * 1024 + k0 + scol, &Bsl[ci * 512]);
    }
    __syncthreads();
#pragma unroll
    for (int kk = 0; kk < 2; ++kk) {
      short8v af[2], bfr[2];
#pragma unroll
      for (int m = 0; m < 2; ++m)
        af[m] = *(const short8v*)&Asl[(wr * 32 + m * 16 + c) * 64 + kk * 32 + g * 8];
#pragma unroll
      for (int n = 0; n < 2; ++n)
        bfr[n] = *(const short8v*)&Bsl[(wc * 32 + n * 16 + c) * 64 + kk * 32 + g * 8];
#pragma unroll
      for (int m = 0; m < 2; ++m)
#pragma unroll
        for (int n = 0; n < 2; ++n) acc[m][n] = MFMA16(af[m], bfr[n], acc[m][n]);
    }
    __syncthreads();
  }

#pragma unroll
  for (int m = 0; m < 2; ++m)
#pragma unroll
    for (int n = 0; n < 2; ++n)
#pragma unroll
      for (int r = 0; r < 4; ++r) {
        int grow = rowBase + wr * 32 + m * 16 + g * 4 + r;
        int gcol = colBase + wc * 32 + n * 16 + c;
        outf[(size_t)grow * 1024 + gcol] = acc[m][n][r] + bias[gcol];
      }
}

// ---------------- flash attention: KV128 + packed bias + permlane + T1 XCD swizzle ----
// No-max softmax (scores bounded: |S*log2e| <= 5.9 by l2-norm construction).
// 4 waves x 32 q-rows = 128 q/block; KV tile 128 (4 sequential 32-k subtiles).
// Bias from B2[plane][q][e] (r19); permlane32_swap A-frag exchange (r21).
// NEW (T1): 1D grid 512, chunked XCD remap — xcd=id&7, vid=xcd*64+(id>>3) —
// bijective (512=8x64); each XCD owns 4 bh x 16 qt -> K/V working set 2MB <= L2.
// NOTE: no min-waves launch bound ((256,4) caused 300MB scratch spills, r6-7).
__global__ __launch_bounds__(256) void attn_fwd(
    const unsigned short* __restrict__ qn, const unsigned short* __restrict__ kn,
    const unsigned short* __restrict__ vt, const unsigned short* __restrict__ biasb,
    unsigned short* __restrict__ oup) {
  __shared__ unsigned short Ksl[2][128][72];
  __shared__ unsigned short Vsl[2][64][136];
  const int tid = threadIdx.x;
  const int lane = tid & 63;
  const int wave = tid >> 6;
  const int c5 = lane & 31;
  const int h = lane >> 5;
  const int id = blockIdx.x;            // 0..511
  const int xcd = id & 7;
  const int vid = xcd * 64 + (id >> 3); // chunked virtual id (bijective)
  const int bh = vid >> 4;              // 4 consecutive bh per XCD
  const int qt = vid & 15;
  const int b = bh >> 4, hd = bh & 15;
  const int q = qt * 128 + wave * 32 + c5;

  short8v qf[4];
  {
    const unsigned short* qp = qn + ((size_t)bh * 2048 + q) * 64 + h * 8;
#pragma unroll
    for (int kd = 0; kd < 4; ++kd) qf[kd] = *(const short8v*)(qp + kd * 16);
  }
  const unsigned short* kb = kn + (size_t)bh * 131072;
  const unsigned short* vb = vt + (size_t)bh * 131072;
  // fragment-packed bias base for this lane: B2[plane][q][e], plane=(kt*4+n)*2+h
  const unsigned short* bq = biasb + (size_t)q * 16 + (size_t)h * 32768;

  int rk[4], ck[4], rv[4], cv[4];
#pragma unroll
  for (int i = 0; i < 4; ++i) {
    int flat = tid * 8 + i * 2048;
    rk[i] = flat >> 6;  ck[i] = flat & 63;
    rv[i] = flat >> 7;  cv[i] = flat & 127;
  }

  int4v kreg[4], vreg[4];
  u16x4 bb[4][4];

  auto ISSUE = [&](int kt) {
#pragma unroll
    for (int i = 0; i < 4; ++i) {
      kreg[i] = *(const int4v*)(kb + (size_t)(kt * 128 + rk[i]) * 64 + ck[i]);
      vreg[i] = *(const int4v*)(vb + (size_t)rv[i] * 2048 + kt * 128 + cv[i]);
    }
  };
  auto ISSUEB = [&](int n, int kt) {
    const unsigned short* p = bq + (size_t)(kt * 4 + n) * 65536;  // *2 planes*32768
#pragma unroll
    for (int Qd = 0; Qd < 4; ++Qd)
      bb[n][Qd] = *(const u16x4*)(p + Qd * 4);
  };
  auto WRITE = [&](int buf) {
#pragma unroll
    for (int i = 0; i < 4; ++i) {
      *(int4v*)&Ksl[buf][rk[i]][ck[i]] = kreg[i];
      *(int4v*)&Vsl[buf][rv[i]][cv[i]] = vreg[i];
    }
  };

  float l_run = 0.0f;
  f32x16 o0 = {}, o1 = {};

  ISSUE(0);
#pragma unroll
  for (int n = 0; n < 4; ++n) ISSUEB(n, 0);
  WRITE(0);
  __syncthreads();

  for (int kt = 0; kt < 16; ++kt) {
    const int cur = kt & 1;
    const bool more = (kt + 1) < 16;
    if (more) ISSUE(kt + 1);
    float rs = 0.0f;

#pragma unroll
    for (int n = 0; n < 4; ++n) {
      f32x16 s;
#pragma unroll
      for (int Qd = 0; Qd < 4; ++Qd)
#pragma unroll
        for (int r = 0; r < 4; ++r) s[Qd * 4 + r] = bf2f(bb[n][Qd][r]);
      if (more) ISSUEB(n, kt + 1);

      __builtin_amdgcn_s_setprio(1);
#pragma unroll
      for (int kd = 0; kd < 4; ++kd) {
        short8v kf = *(const short8v*)&Ksl[cur][n * 32 + c5][kd * 16 + h * 8];
        s = MFMA32(kf, qf[kd], s);
      }
      __builtin_amdgcn_s_setprio(0);

#pragma unroll
      for (int e = 0; e < 16; ++e) {
        float p = exp2_hw(s[e]);
        s[e] = p;
        rs += p;
      }

      unsigned int w[4][2];
#pragma unroll
      for (int Qd = 0; Qd < 4; ++Qd) {
        asm("v_cvt_pk_bf16_f32 %0, %1, %2"
            : "=v"(w[Qd][0]) : "v"(s[Qd * 4 + 0]), "v"(s[Qd * 4 + 1]));
        asm("v_cvt_pk_bf16_f32 %0, %1, %2"
            : "=v"(w[Qd][1]) : "v"(s[Qd * 4 + 2]), "v"(s[Qd * 4 + 3]));
      }

      // A-frags via v_permlane32_swap (r21): swap(A,B) -> A'[32+i]=B[i],
      // B'[i]=A[32+i]; reading A',B' at own lane reproduces the old
      // select+shfl_xor(32)+select exchange exactly.
      __builtin_amdgcn_s_setprio(1);
#pragma unroll
      for (int kc = 0; kc < 2; ++kc) {
        unsigned int a0 = w[kc * 2][0], a1 = w[kc * 2][1];
        unsigned int b0 = w[kc * 2 + 1][0], b1 = w[kc * 2 + 1][1];
        asm volatile("v_permlane32_swap_b32 %0, %1" : "+v"(a0), "+v"(b0));
        asm volatile("v_permlane32_swap_b32 %0, %1" : "+v"(a1), "+v"(b1));
        uint4v wv = {a0, a1, b0, b1};
        short8v pa = __builtin_bit_cast(short8v, wv);
        short8v v0 = *(const short8v*)&Vsl[cur][c5][n * 32 + kc * 16 + h * 8];
        short8v v1 = *(const short8v*)&Vsl[cur][32 + c5][n * 32 + kc * 16 + h * 8];
        o0 = MFMA32(pa, v0, o0);
        o1 = MFMA32(pa, v1, o1);
      }
      __builtin_amdgcn_s_setprio(0);
    }

    rs += __shfl_xor(rs, 32);
    l_run += rs;

    if (more) WRITE(cur ^ 1);
    __syncthreads();
  }

  float linv = 1.0f / l_run;
#pragma unroll
  for (int e = 0; e < 16; ++e) {
    int ql = (e & 3) + 8 * (e >> 2) + 4 * h;
    float inv = __shfl(linv, ql);
    int grow = b * 2048 + qt * 128 + wave * 32 + ql;
    oup[(size_t)grow * 1024 + hd * 64 + c5] = f2bf(o0[e] * inv);
    oup[(size_t)grow * 1024 + hd * 64 + 32 + c5] = f2bf(o1[e] * inv);
  }
}

// ---------------- host launch ----------------
extern "C" void kernel_launch(void* const* d_in, const int* in_sizes, int n_in,
                              void* d_out, int out_size, void* d_ws, size_t ws_size,
                              hipStream_t stream) {
  const float* x = (const float*)d_in[0];
  const float* attn_bias = (const float*)d_in[1];
  const float* w_qkv = (const float*)d_in[2];
  const float* q_bias = (const float*)d_in[3];
  const float* v_bias = (const float*)d_in[4];
  const float* scale_mul = (const float*)d_in[5];
  const float* w_proj = (const float*)d_in[6];
  const float* b_proj = (const float*)d_in[7];
  float* out = (float*)d_out;

  char* ws = (char*)d_ws;
  unsigned short* xb = (unsigned short*)(ws);                   // [4096][1024] bf16
  unsigned short* oup = (unsigned short*)(ws);                  // alias (disjoint lifetime)
  unsigned short* wqkvb = (unsigned short*)(ws + (8 << 20));    // [3072][1024]
  unsigned short* wprojb = (unsigned short*)(ws + (14 << 20));  // [1024][1024]
  unsigned short* biasb = (unsigned short*)(ws + (16 << 20));   // B2 [128][2048][16] (*log2e)
  unsigned short* qn = (unsigned short*)(ws + (24 << 20));      // [32][2048][64]
  unsigned short* kn = (unsigned short*)(ws + (32 << 20));      // [32][2048][64]
  unsigned short* vt = (unsigned short*)(ws + (40 << 20));      // [32][64][2048]

  prep_all<<<9216, 256, 0, stream>>>(x, w_qkv, w_proj, attn_bias, xb, wqkvb,
                                     wprojb, biasb);
  gemm_qkv<<<dim3(16, 12), 512, 0, stream>>>(xb, wqkvb, qn, kn, vt, q_bias,
                                             v_bias, scale_mul);
  attn_fwd<<<512, 256, 0, stream>>>(qn, kn, vt, biasb, oup);
  gemm_proj<<<dim3(64, 16), 256, 0, stream>>>(oup, wprojb, out, b_proj);
}